// Round 2
// 1042.821 us; speedup vs baseline: 1.2150x; 1.2150x over previous
//
#include <hip/hip_runtime.h>
#include <math.h>

typedef float f4 __attribute__((ext_vector_type(4)));
typedef float f32x4 __attribute__((ext_vector_type(4)));
typedef __bf16 bf16;
typedef bf16 bf16x8 __attribute__((ext_vector_type(8)));
typedef unsigned short us8 __attribute__((ext_vector_type(8)));

#define LOGIT_MAX_F 4.605170185988092f

// ---------------------------------------------------------------- bf16 helpers
__device__ __forceinline__ unsigned short bf_rne(float x) {
  unsigned u = __float_as_uint(x);
  u += 0x7fff + ((u >> 16) & 1);
  return (unsigned short)(u >> 16);
}
__device__ __forceinline__ float bf_to_f(unsigned short h) {
  return __uint_as_float((unsigned)h << 16);
}
__device__ __forceinline__ void stage16(const unsigned short* g, unsigned short* l) {
  __builtin_amdgcn_global_load_lds(
      (const __attribute__((address_space(1))) unsigned int*)g,
      (__attribute__((address_space(3))) unsigned int*)l, 16, 0, 0);
}

// ---------------------------------------------------------------- CPB tables
__global__ __launch_bounds__(64) void k_cpb(const float* __restrict__ w1,
                                            const float* __restrict__ b1,
                                            const float* __restrict__ w2,
                                            float* __restrict__ sbt,
                                            int n_cw, float inv_p0, float inv_p1,
                                            int ts_n0, int ts_n1) {
  int row = blockIdx.x;
  int lane = threadIdx.x;
  int ih = row / n_cw, iw = row % n_cw;
  float v0 = (float)(ts_n0 + ih) * inv_p0 * 8.0f;
  float v1 = (float)(ts_n1 + iw) * inv_p1 * 8.0f;
  v0 = (v0 >= 0.f ? 1.f : -1.f) * log2f(fabsf(v0) + 1.f) * (1.f / 3.f);
  v1 = (v1 >= 0.f ? 1.f : -1.f) * log2f(fabsf(v1) + 1.f) * (1.f / 3.f);
  float a0 = 0.f, a1 = 0.f, a2 = 0.f, a3 = 0.f;
  for (int j = lane; j < 512; j += 64) {
    float h = v0 * w1[j] + v1 * w1[512 + j] + b1[j];
    h = fmaxf(h, 0.f);
    a0 += h * w2[j * 4 + 0];
    a1 += h * w2[j * 4 + 1];
    a2 += h * w2[j * 4 + 2];
    a3 += h * w2[j * 4 + 3];
  }
#pragma unroll
  for (int off = 32; off > 0; off >>= 1) {
    a0 += __shfl_down(a0, off);
    a1 += __shfl_down(a1, off);
    a2 += __shfl_down(a2, off);
    a3 += __shfl_down(a3, off);
  }
  if (lane == 0) {
    sbt[row * 4 + 0] = 16.f / (1.f + expf(-a0));
    sbt[row * 4 + 1] = 16.f / (1.f + expf(-a1));
    sbt[row * 4 + 2] = 16.f / (1.f + expf(-a2));
    sbt[row * 4 + 3] = 16.f / (1.f + expf(-a3));
  }
}

// ---------------------------------------------------------------- 4x4 mean pool
__global__ __launch_bounds__(256) void k_pool(const float* __restrict__ x,
                                              float* __restrict__ pooled) {
  int blk = blockIdx.x;            // (b, gi, gj)
  int c = threadIdx.x;
  int b = blk >> 8, gi = (blk >> 4) & 15, gj = blk & 15;
  const float* xp = x + (size_t)b * 4096 * 256 + c;
  float s = 0.f;
#pragma unroll
  for (int di = 0; di < 4; di++)
#pragma unroll
    for (int dj = 0; dj < 4; dj++)
      s += xp[(size_t)((gi * 4 + di) * 64 + gj * 4 + dj) * 256];
  pooled[(size_t)blk * 256 + c] = s * 0.0625f;
}

// ---------------------------------------------------------------- f32 GEMM 64-tile (small, anchor only)
__global__ __launch_bounds__(256) void k_gemm(const float* __restrict__ A,
                                              const float* __restrict__ W,
                                              const float* __restrict__ bias,
                                              float* __restrict__ C,
                                              int M, int N, int K, int ldw) {
  __shared__ float a_s[16][64];
  __shared__ float w_s[16][64];
  const int ntg = N >> 6;
  const int mb = blockIdx.x / ntg, nb = blockIdx.x % ntg;
  const int m0 = mb << 6, n0 = nb << 6;
  const int tid = threadIdx.x;
  const int tx = tid & 15, ty = tid >> 4;
  const int ar = tid >> 2, ac4 = (tid & 3) << 2;
  const int wk = tid >> 4, wc4 = (tid & 15) << 2;
  float acc[4][4] = {};
  for (int k0 = 0; k0 < K; k0 += 16) {
    f4 av = *(const f4*)(A + (size_t)(m0 + ar) * K + k0 + ac4);
    f4 wv = *(const f4*)(W + (size_t)(k0 + wk) * ldw + n0 + wc4);
    __syncthreads();
    a_s[ac4 + 0][ar] = av[0];
    a_s[ac4 + 1][ar] = av[1];
    a_s[ac4 + 2][ar] = av[2];
    a_s[ac4 + 3][ar] = av[3];
    *(f4*)(&w_s[wk][wc4]) = wv;
    __syncthreads();
#pragma unroll
    for (int kk = 0; kk < 16; kk++) {
      f4 a4 = *(const f4*)(&a_s[kk][ty << 2]);
      f4 w4 = *(const f4*)(&w_s[kk][tx << 2]);
#pragma unroll
      for (int i = 0; i < 4; i++)
#pragma unroll
        for (int j = 0; j < 4; j++)
          acc[i][j] = fmaf(a4[i], w4[j], acc[i][j]);
    }
  }
#pragma unroll
  for (int i = 0; i < 4; i++) {
    const int row = m0 + (ty << 2) + i;
#pragma unroll
    for (int j = 0; j < 4; j++) {
      const int col = n0 + (tx << 2) + j;
      C[(size_t)row * N + col] = acc[i][j] + bias[col];
    }
  }
}

// ---------------------------------------------------------------- f32 -> bf16 hi/lo pair
// total elements must be a multiple of 2048; grid = total/2048, block 256
__global__ __launch_bounds__(256) void k_cvt(const float* __restrict__ in,
                                             unsigned short* __restrict__ hi,
                                             unsigned short* __restrict__ lo) {
  const size_t i = ((size_t)blockIdx.x * 256 + threadIdx.x) * 8;
  f4 v0 = *(const f4*)(in + i);
  f4 v1 = *(const f4*)(in + i + 4);
  us8 h, l;
#pragma unroll
  for (int e = 0; e < 8; e++) {
    float xv = e < 4 ? v0[e] : v1[e - 4];
    unsigned short hh = bf_rne(xv);
    h[e] = hh;
    l[e] = bf_rne(xv - bf_to_f(hh));
  }
  *(us8*)(hi + i) = h;
  *(us8*)(lo + i) = l;
}

// ---------------------------------------------------------------- weight convert + transpose
// W f32 [256][N] -> Wt hi/lo bf16 [N][256]; grid = N blocks, 256 threads
__global__ __launch_bounds__(256) void k_cvt_wt(const float* __restrict__ W,
                                                unsigned short* __restrict__ hi,
                                                unsigned short* __restrict__ lo,
                                                int N) {
  const int n = blockIdx.x, k = threadIdx.x;
  float xv = W[(size_t)k * N + n];
  unsigned short hh = bf_rne(xv);
  hi[n * 256 + k] = hh;
  lo[n * 256 + k] = bf_rne(xv - bf_to_f(hh));
}

// ---------------------------------------------------------------- split-bf16 MFMA GEMM
// C[M][N] f32 = A[M][256] @ B[256][N] + bias, where A given as (Ahi+Alo) bf16 and
// B given transposed as Bt[N][256] bf16 hi/lo.  acc = Ah*Bh + Ah*Bl + Al*Bh (f32 acc).
// tile 128x128, BK=32, 256 threads = 4 waves (2x2), each wave 64x64 = 4x4 frags 16x16.
// M%128==0, N%128==0, K fixed at 256.
__global__ __launch_bounds__(256) void k_gemm_bf16pair(
    const unsigned short* __restrict__ Ahi, const unsigned short* __restrict__ Alo,
    const unsigned short* __restrict__ Bthi, const unsigned short* __restrict__ Btlo,
    const float* __restrict__ bias, float* __restrict__ C, int M, int N) {
  __shared__ __align__(16) unsigned short ah_s[128 * 32];
  __shared__ __align__(16) unsigned short al_s[128 * 32];
  __shared__ __align__(16) unsigned short bh_s[128 * 32];
  __shared__ __align__(16) unsigned short bl_s[128 * 32];
  const int ntg = N >> 7;
  const int m0 = (blockIdx.x / ntg) << 7, n0 = (blockIdx.x % ntg) << 7;
  const int tid = threadIdx.x;
  const int w = tid >> 6, l = tid & 63;
  const int wr = w >> 1, wc = w & 1;     // wave grid 2x2
  const int lr = l & 15, kg = l >> 4;    // MFMA lane row / k-group
  // staging: thread t loads 8 contiguous bf16 (16B); wave w covers 16 rows
  const int srow = tid >> 2;             // 0..63
  const int scol = (tid & 3) << 3;       // 0,8,16,24
  const int lds_w = w * 512;             // per-wave dest base (ushort units)
  f32x4 acc[4][4] = {};

  for (int k0 = 0; k0 < 256; k0 += 32) {
    const size_t ga0 = (size_t)(m0 + srow) * 256 + k0 + scol;
    const size_t ga1 = (size_t)(m0 + 64 + srow) * 256 + k0 + scol;
    const size_t gb0 = (size_t)(n0 + srow) * 256 + k0 + scol;
    const size_t gb1 = (size_t)(n0 + 64 + srow) * 256 + k0 + scol;
    stage16(Ahi + ga0, ah_s + lds_w);
    stage16(Ahi + ga1, ah_s + 2048 + lds_w);
    stage16(Alo + ga0, al_s + lds_w);
    stage16(Alo + ga1, al_s + 2048 + lds_w);
    stage16(Bthi + gb0, bh_s + lds_w);
    stage16(Bthi + gb1, bh_s + 2048 + lds_w);
    stage16(Btlo + gb0, bl_s + lds_w);
    stage16(Btlo + gb1, bl_s + 2048 + lds_w);
    __syncthreads();   // compiler drains vmcnt(0) before s_barrier
    bf16x8 a_h[4], a_l[4], b_h[4], b_l[4];
#pragma unroll
    for (int i = 0; i < 4; i++) {
      const int r = wr * 64 + i * 16 + lr;
      a_h[i] = *(const bf16x8*)(ah_s + r * 32 + kg * 8);
      a_l[i] = *(const bf16x8*)(al_s + r * 32 + kg * 8);
    }
#pragma unroll
    for (int j = 0; j < 4; j++) {
      const int r = wc * 64 + j * 16 + lr;
      b_h[j] = *(const bf16x8*)(bh_s + r * 32 + kg * 8);
      b_l[j] = *(const bf16x8*)(bl_s + r * 32 + kg * 8);
    }
#pragma unroll
    for (int i = 0; i < 4; i++)
#pragma unroll
      for (int j = 0; j < 4; j++) {
        acc[i][j] = __builtin_amdgcn_mfma_f32_16x16x32_bf16(a_h[i], b_h[j], acc[i][j], 0, 0, 0);
        acc[i][j] = __builtin_amdgcn_mfma_f32_16x16x32_bf16(a_h[i], b_l[j], acc[i][j], 0, 0, 0);
        acc[i][j] = __builtin_amdgcn_mfma_f32_16x16x32_bf16(a_l[i], b_h[j], acc[i][j], 0, 0, 0);
      }
    __syncthreads();   // protect LDS from next iteration's staging
  }
  // epilogue: D row = (l>>4)*4 + r, col = l&15  (verified gfx950 C/D layout)
#pragma unroll
  for (int j = 0; j < 4; j++) {
    const int col = n0 + wc * 64 + j * 16 + lr;
    const float bj = bias[col];
#pragma unroll
    for (int i = 0; i < 4; i++) {
      const int row0 = m0 + wr * 64 + i * 16 + kg * 4;
#pragma unroll
      for (int r = 0; r < 4; r++)
        C[(size_t)(row0 + r) * N + col] = acc[i][j][r] + bj;
    }
  }
}

// ---------------------------------------------------------------- window attention
__global__ __launch_bounds__(256) void k_win_attn(const float* __restrict__ qkvw,
                                                  const float* __restrict__ sbt,
                                                  const float* __restrict__ ls,
                                                  float* __restrict__ outp) {
  __shared__ float k_s[256][32];
  __shared__ float kinv[256];
  __shared__ float bias_s[961];
  const int head = blockIdx.x & 3, win = blockIdx.x >> 2;
  const int b = win >> 4, wh = (win >> 2) & 3, ww = win & 3;
  const size_t rowbase = (size_t)b * 4096 + wh * 1024 + ww * 16;
  const int tid = threadIdx.x;
  const float escale = __expf(fminf(ls[head], LOGIT_MAX_F));
  {  // stage K row `tid` + inv-norm
    const float* kp = qkvw + (rowbase + (tid >> 4) * 64 + (tid & 15)) * 384 + 128 + head * 32;
    float ss = 0.f;
#pragma unroll
    for (int c = 0; c < 8; c++) {
      f4 kv = *(const f4*)(kp + c * 4);
      *(f4*)(&k_s[tid][c * 4]) = kv;
      ss += kv[0] * kv[0] + kv[1] * kv[1] + kv[2] * kv[2] + kv[3] * kv[3];
    }
    kinv[tid] = 1.f / fmaxf(sqrtf(ss), 1e-12f);
  }
  for (int i = tid; i < 961; i += 256) bias_s[i] = sbt[i * 4 + head];
  __syncthreads();

  const int qi = tid >> 4, qj = tid & 15;
  const float* qp = qkvw + (rowbase + qi * 64 + qj) * 384 + head * 32;
  f4 q8[8];
  float qss = 0.f;
#pragma unroll
  for (int c = 0; c < 8; c++) {
    q8[c] = *(const f4*)(qp + c * 4);
    qss += q8[c][0] * q8[c][0] + q8[c][1] * q8[c][1] + q8[c][2] * q8[c][2] + q8[c][3] * q8[c][3];
  }
  const float qsc = escale / fmaxf(sqrtf(qss), 1e-12f);

  float mx = -1e30f, rs = 0.f;
  f4 o8[8] = {};
#pragma unroll 1
  for (int ki = 0; ki < 16; ki++) {   // chunk = window-row of 16 keys
    const int bbase = (qi - ki + 15) * 31 + qj + 15;
    float s16[16];
    float cmx = -1e30f;
#pragma unroll
    for (int kj = 0; kj < 16; kj++) {
      const int key = ki * 16 + kj;
      float s = 0.f;
#pragma unroll
      for (int c = 0; c < 8; c++) {
        f4 kv = *(const f4*)(&k_s[key][c * 4]);
        s = fmaf(q8[c][0], kv[0], s); s = fmaf(q8[c][1], kv[1], s);
        s = fmaf(q8[c][2], kv[2], s); s = fmaf(q8[c][3], kv[3], s);
      }
      s = s * qsc * kinv[key] + bias_s[bbase - kj];
      s16[kj] = s;
      cmx = fmaxf(cmx, s);
    }
    const float nmx = fmaxf(mx, cmx);
    const float alpha = __expf(mx - nmx);
    rs *= alpha;
#pragma unroll
    for (int c = 0; c < 8; c++) o8[c] *= alpha;
    mx = nmx;
#pragma unroll
    for (int kj = 0; kj < 16; kj++) {
      const float p = __expf(s16[kj] - mx);
      rs += p;
      const float* vp = qkvw + (rowbase + ki * 64 + kj) * 384 + 256 + head * 32;
#pragma unroll
      for (int c = 0; c < 8; c++) {
        f4 vv = *(const f4*)(vp + c * 4);
        o8[c] += vv * p;
      }
    }
  }
  const float inv = 1.f / rs;
  float* op = outp + (rowbase + qi * 64 + qj) * 256 + head * 32;
#pragma unroll
  for (int c = 0; c < 8; c++) {
    f4 v = o8[c] * inv;
    *(f4*)(op + c * 4) = v;
  }
}

// ---------------------------------------------------------------- stripe stage 1
__global__ __launch_bounds__(256) void k_stripe1(const float* __restrict__ qkvs,
                                                 const float* __restrict__ anch,
                                                 const float* __restrict__ sbt,
                                                 const float* __restrict__ ls,
                                                 float* __restrict__ tbuf) {
  __shared__ float kinv_s[1024];
  __shared__ float ansc[64];
  __shared__ float bias_s[1501];
  __shared__ float mxred[64][4];
  __shared__ float rsred[64][4];
  __shared__ float opart[64][4][33];
  const int head = blockIdx.x & 3, sb = blockIdx.x >> 2;
  const int b = sb >> 2, wj = sb & 3;
  const size_t rowbase = (size_t)b * 4096 + wj * 16;
  const size_t abase = (size_t)b * 256 + wj * 4;
  const int tid = threadIdx.x;
  const int q = tid & 63, sl = tid >> 6;
  const float escale = __expf(fminf(ls[head], LOGIT_MAX_F));
  for (int tt = tid; tt < 1024; tt += 256) {  // precompute key inv-norms
    const float* kp = qkvs + (rowbase + (tt >> 4) * 64 + (tt & 15)) * 384 + 128 + head * 32;
    float ss = 0.f;
#pragma unroll
    for (int c = 0; c < 8; c++) {
      f4 kv = *(const f4*)(kp + c * 4);
      ss += kv[0] * kv[0] + kv[1] * kv[1] + kv[2] * kv[2] + kv[3] * kv[3];
    }
    kinv_s[tt] = 1.f / fmaxf(sqrtf(ss), 1e-12f);
  }
  if (tid < 64) {
    const float* ap = anch + (abase + (tid >> 2) * 16 + (tid & 3)) * 128 + head * 32;
    float ss = 0.f;
#pragma unroll
    for (int c = 0; c < 8; c++) {
      f4 v = *(const f4*)(ap + c * 4);
      ss += v[0] * v[0] + v[1] * v[1] + v[2] * v[2] + v[3] * v[3];
    }
    ansc[tid] = 1.f / fmaxf(sqrtf(ss), 1e-12f);
  }
  for (int i = tid; i < 1501; i += 256) bias_s[i] = sbt[i * 4 + head];
  __syncthreads();

  const float* qp = anch + (abase + (q >> 2) * 16 + (q & 3)) * 128 + head * 32;
  f4 q8[8];
#pragma unroll
  for (int c = 0; c < 8; c++) q8[c] = *(const f4*)(qp + c * 4);
  const float qsc = escale * ansc[q];
  const int ah = q >> 2, aw = q & 3;

  float mx = -1e30f, rs = 0.f;
  f4 o8[8] = {};
#pragma unroll 1
  for (int cc = 0; cc < 16; cc++) {          // chunk = one stripe row ti
    const int ti = sl * 16 + cc;
    const int bb = (ah - ti + 63) * 19 + aw + 15;
    const float* rowp = qkvs + (rowbase + ti * 64) * 384 + head * 32;
    float s16[16];
    float cmx = -1e30f;
#pragma unroll
    for (int tj = 0; tj < 16; tj++) {
      const float* kp = rowp + tj * 384 + 128;
      float s = 0.f;
#pragma unroll
      for (int c = 0; c < 8; c++) {
        f4 kv = *(const f4*)(kp + c * 4);
        s = fmaf(q8[c][0], kv[0], s); s = fmaf(q8[c][1], kv[1], s);
        s = fmaf(q8[c][2], kv[2], s); s = fmaf(q8[c][3], kv[3], s);
      }
      s = s * qsc * kinv_s[ti * 16 + tj] + bias_s[bb - tj];
      s16[tj] = s;
      cmx = fmaxf(cmx, s);
    }
    const float nmx = fmaxf(mx, cmx);
    const float alpha = __expf(mx - nmx);
    rs *= alpha;
#pragma unroll
    for (int c = 0; c < 8; c++) o8[c] *= alpha;
    mx = nmx;
#pragma unroll
    for (int tj = 0; tj < 16; tj++) {
      const float p = __expf(s16[tj] - mx);
      rs += p;
      const float* vp = rowp + tj * 384 + 256;
#pragma unroll
      for (int c = 0; c < 8; c++) {
        f4 vv = *(const f4*)(vp + c * 4);
        o8[c] += vv * p;
      }
    }
  }
  mxred[q][sl] = mx;
  __syncthreads();
  const float mxg = fmaxf(fmaxf(mxred[q][0], mxred[q][1]), fmaxf(mxred[q][2], mxred[q][3]));
  const float w = __expf(mx - mxg);
  rsred[q][sl] = rs * w;
#pragma unroll
  for (int c = 0; c < 8; c++) {
    opart[q][sl][c * 4 + 0] = o8[c][0] * w;
    opart[q][sl][c * 4 + 1] = o8[c][1] * w;
    opart[q][sl][c * 4 + 2] = o8[c][2] * w;
    opart[q][sl][c * 4 + 3] = o8[c][3] * w;
  }
  __syncthreads();
  {
    const int q2 = tid >> 2, cg = (tid & 3) << 3;
    const float inv = 1.f / (rsred[q2][0] + rsred[q2][1] + rsred[q2][2] + rsred[q2][3]);
    float* tp = tbuf + (size_t)blockIdx.x * 2048 + q2 * 32 + cg;
#pragma unroll
    for (int i = 0; i < 8; i++) {
      const int c = cg + i;
      tp[i] = (opart[q2][0][c] + opart[q2][1][c] + opart[q2][2][c] + opart[q2][3][c]) * inv;
    }
  }
}

// ---------------------------------------------------------------- stripe stage 2
__global__ __launch_bounds__(256) void k_stripe2(const float* __restrict__ qkvs,
                                                 const float* __restrict__ anch,
                                                 const float* __restrict__ tbuf,
                                                 const float* __restrict__ sbt,
                                                 const float* __restrict__ ls,
                                                 float* __restrict__ outp) {
  __shared__ float a_s[64][32];
  __shared__ float t_s[64][32];
  __shared__ float ansc[64];
  __shared__ float bias_s[1501];
  const int head = blockIdx.x & 3, sb = blockIdx.x >> 2;
  const int b = sb >> 2, wj = sb & 3;
  const size_t rowbase = (size_t)b * 4096 + wj * 16;
  const size_t abase = (size_t)b * 256 + wj * 4;
  const int tid = threadIdx.x;
  const float escale = __expf(fminf(ls[head], LOGIT_MAX_F));
  if (tid < 64) {
    const float* ap = anch + (abase + (tid >> 2) * 16 + (tid & 3)) * 128 + head * 32;
    const float* tp = tbuf + (size_t)blockIdx.x * 2048 + tid * 32;
    float ss = 0.f;
#pragma unroll
    for (int c = 0; c < 8; c++) {
      f4 v = *(const f4*)(ap + c * 4);
      *(f4*)(&a_s[tid][c * 4]) = v;
      ss += v[0] * v[0] + v[1] * v[1] + v[2] * v[2] + v[3] * v[3];
      *(f4*)(&t_s[tid][c * 4]) = *(const f4*)(tp + c * 4);
    }
    ansc[tid] = 1.f / fmaxf(sqrtf(ss), 1e-12f);
  }
  for (int i = tid; i < 1501; i += 256) bias_s[i] = sbt[i * 4 + head];
  __syncthreads();

#pragma unroll 1
  for (int rep = 0; rep < 4; rep++) {
    const int qt = rep * 256 + tid;
    const int ti = qt >> 4, tj = qt & 15;
    const float* qp = qkvs + (rowbase + ti * 64 + tj) * 384 + head * 32;
    f4 q8[8];
    float qss = 0.f;
#pragma unroll
    for (int c = 0; c < 8; c++) {
      q8[c] = *(const f4*)(qp + c * 4);
      qss += q8[c][0] * q8[c][0] + q8[c][1] * q8[c][1] + q8[c][2] * q8[c][2] + q8[c][3] * q8[c][3];
    }
    const float qsc = escale / fmaxf(sqrtf(qss), 1e-12f);
    float sarr[64];
    float mx = -1e30f;
#pragma unroll 1
    for (int a = 0; a < 64; a++) {
      float s = 0.f;
#pragma unroll
      for (int c = 0; c < 8; c++) {
        f4 kv = *(const f4*)(&a_s[a][c * 4]);
        s = fmaf(q8[c][0], kv[0], s); s = fmaf(q8[c][1], kv[1], s);
        s = fmaf(q8[c][2], kv[2], s); s = fmaf(q8[c][3], kv[3], s);
      }
      s = s * qsc * ansc[a] + bias_s[(ti - (a >> 2) + 15) * 19 + (tj - (a & 3) + 3)];
      sarr[a] = s;
      mx = fmaxf(mx, s);
    }
    f4 o8[8] = {};
    float rs = 0.f;
#pragma unroll 1
    for (int a = 0; a < 64; a++) {
      const float p = __expf(sarr[a] - mx);
      rs += p;
#pragma unroll
      for (int c = 0; c < 8; c++) {
        f4 tv = *(const f4*)(&t_s[a][c * 4]);
        o8[c] += tv * p;
      }
    }
    const float inv = 1.f / rs;
    float* op = outp + (rowbase + ti * 64 + tj) * 256 + 128 + head * 32;
#pragma unroll
    for (int c = 0; c < 8; c++) {
      f4 v = o8[c] * inv;
      *(f4*)(op + c * 4) = v;
    }
  }
}

// ---------------------------------------------------------------- launch
extern "C" void kernel_launch(void* const* d_in, const int* in_sizes, int n_in,
                              void* d_out, int out_size, void* d_ws, size_t ws_size,
                              hipStream_t stream) {
  (void)in_sizes; (void)n_in; (void)out_size;
  const float* x        = (const float*)d_in[0];
  const float* w_qkv    = (const float*)d_in[1];
  const float* b_qkv    = (const float*)d_in[2];
  const float* w_anchor = (const float*)d_in[3];
  const float* b_anchor = (const float*)d_in[4];
  const float* ls_w     = (const float*)d_in[5];
  const float* cw1_w    = (const float*)d_in[6];
  const float* cb1_w    = (const float*)d_in[7];
  const float* cw2_w    = (const float*)d_in[8];
  const float* ls_s1    = (const float*)d_in[9];
  const float* cw1_s1   = (const float*)d_in[10];
  const float* cb1_s1   = (const float*)d_in[11];
  const float* cw2_s1   = (const float*)d_in[12];
  const float* ls_s2    = (const float*)d_in[13];
  const float* cw1_s2   = (const float*)d_in[14];
  const float* cb1_s2   = (const float*)d_in[15];
  const float* cw2_s2   = (const float*)d_in[16];
  const float* w_proj   = (const float*)d_in[17];
  const float* b_proj   = (const float*)d_in[18];
  float* out = (float*)d_out;

  // ---- adaptive chunking over batch
  const size_t fixed_bytes =
      (size_t)4096 * 256 * 4 +          // pooled
      (size_t)4096 * 128 * 4 +          // anch
      (size_t)961 * 16 + (size_t)1501 * 16 * 2 +
      (size_t)(768 + 256) * 256 * 2 * 2 +  // transposed bf16 weights hi+lo
      64 * 256;                          // slack
  // per-NB: qkvh f32 + tbuf + x hi/lo bf16
  const size_t per_nb = (size_t)4096 * 384 * 4 + (size_t)16 * 2048 * 4 +
                        (size_t)4096 * 256 * 2 * 2;
  int NB = 16;
  while (NB > 1) {
    size_t need = fixed_bytes + (size_t)NB * per_nb;
    if (need <= ws_size) break;
    NB >>= 1;
  }
  const int nchunks = 16 / NB;

  char* ws = (char*)d_ws;
  size_t off = 0;
  auto take = [&](size_t bytes) {
    char* p = ws + off;
    off += (bytes + 255) & ~(size_t)255;
    return p;
  };
  float* pooled = (float*)take((size_t)4096 * 256 * 4);
  float* anch   = (float*)take((size_t)4096 * 128 * 4);
  float* sbt_w  = (float*)take((size_t)961 * 16);
  float* sbt_s1 = (float*)take((size_t)1501 * 16);
  float* sbt_s2 = (float*)take((size_t)1501 * 16);
  unsigned short* wqh = (unsigned short*)take((size_t)768 * 256 * 2);
  unsigned short* wql = (unsigned short*)take((size_t)768 * 256 * 2);
  unsigned short* wph = (unsigned short*)take((size_t)256 * 256 * 2);
  unsigned short* wpl = (unsigned short*)take((size_t)256 * 256 * 2);
  float* tbuf   = (float*)take((size_t)NB * 16 * 2048 * 4);
  unsigned short* xhi = (unsigned short*)take((size_t)NB * 4096 * 256 * 2);
  unsigned short* xlo = (unsigned short*)take((size_t)NB * 4096 * 256 * 2);
  float* qkvh   = (float*)take((size_t)NB * 4096 * 384 * 4);

  // ---- one-time prep
  k_cpb<<<961, 64, 0, stream>>>(cw1_w, cb1_w, cw2_w, sbt_w, 31, 1.f / 15.f, 1.f / 15.f, -15, -15);
  k_cpb<<<1501, 64, 0, stream>>>(cw1_s1, cb1_s1, cw2_s1, sbt_s1, 19, 1.f / 39.f, 1.f / 9.f, -39, -9);
  k_cpb<<<1501, 64, 0, stream>>>(cw1_s2, cb1_s2, cw2_s2, sbt_s2, 19, 1.f / 39.f, 1.f / 9.f, -39, -9);
  k_cvt_wt<<<768, 256, 0, stream>>>(w_qkv, wqh, wql, 768);
  k_cvt_wt<<<256, 256, 0, stream>>>(w_proj, wph, wpl, 256);
  k_pool<<<4096, 256, 0, stream>>>(x, pooled);
  k_gemm<<<(4096 / 64) * 2, 256, 0, stream>>>(pooled, w_anchor, b_anchor, anch, 4096, 128, 256, 128);

  // ---- chunked over batch
  const int M = NB * 4096;
  for (int c = 0; c < nchunks; c++) {
    const float* xc = x + (size_t)c * NB * 4096 * 256;
    float* outc = out + (size_t)c * NB * 4096 * 256;
    const float* anchc = anch + (size_t)c * NB * 256 * 128;
    // x -> bf16 hi/lo (reused by both qkv halves)
    k_cvt<<<NB * 512, 256, 0, stream>>>(xc, xhi, xlo);
    // window half (qkv channels 0..383)
    k_gemm_bf16pair<<<(M / 128) * 3, 256, 0, stream>>>(xhi, xlo, wqh, wql, b_qkv, qkvh, M, 384);
    k_win_attn<<<NB * 64, 256, 0, stream>>>(qkvh, sbt_w, ls_w, outc);
    // stripe half (qkv channels 384..767) overwrites qkvh
    k_gemm_bf16pair<<<(M / 128) * 3, 256, 0, stream>>>(xhi, xlo, wqh + 384 * 256, wql + 384 * 256,
                                                       b_qkv + 384, qkvh, M, 384);
    k_stripe1<<<NB * 16, 256, 0, stream>>>(qkvh, anchc, sbt_s1, ls_s1, tbuf);
    k_stripe2<<<NB * 16, 256, 0, stream>>>(qkvh, anchc, tbuf, sbt_s2, ls_s2, outc);
  }
  // ---- final projection (reads bf16 copy of out, writes out -> no aliasing hazard)
  for (int c = 0; c < nchunks; c++) {
    float* outc = out + (size_t)c * NB * 4096 * 256;
    k_cvt<<<NB * 512, 256, 0, stream>>>(outc, xhi, xlo);
    k_gemm_bf16pair<<<(M / 128) * 2, 256, 0, stream>>>(xhi, xlo, wph, wpl, b_proj, outc, M, 256);
  }
}

// Round 3
// 875.952 us; speedup vs baseline: 1.4465x; 1.1905x over previous
//
#include <hip/hip_runtime.h>
#include <math.h>

typedef float f4 __attribute__((ext_vector_type(4)));
typedef float f32x4 __attribute__((ext_vector_type(4)));
typedef float f32x16 __attribute__((ext_vector_type(16)));
typedef __bf16 bf16;
typedef bf16 bf16x8 __attribute__((ext_vector_type(8)));
typedef unsigned short us8 __attribute__((ext_vector_type(8)));

#define LOGIT_MAX_F 4.605170185988092f

// ---------------------------------------------------------------- bf16 helpers
__device__ __forceinline__ unsigned short bf_rne(float x) {
  unsigned u = __float_as_uint(x);
  u += 0x7fff + ((u >> 16) & 1);
  return (unsigned short)(u >> 16);
}
__device__ __forceinline__ float bf_to_f(unsigned short h) {
  return __uint_as_float((unsigned)h << 16);
}
__device__ __forceinline__ void stage16(const unsigned short* g, unsigned short* l) {
  __builtin_amdgcn_global_load_lds(
      (const __attribute__((address_space(1))) unsigned int*)g,
      (__attribute__((address_space(3))) unsigned int*)l, 16, 0, 0);
}
// packed f32x2 -> bf16x2 (RNE), no builtin on gfx950 -> inline asm
__device__ __forceinline__ unsigned cvt_pk_bf16(float a, float b) {
  unsigned r;
  asm("v_cvt_pk_bf16_f32 %0, %1, %2" : "=v"(r) : "v"(a), "v"(b));
  return r;
}
// lane i <-> lane i+32 half-exchange; s_nops guard VALU<->permlane hazards
__device__ __forceinline__ void pl32swap(unsigned& a, unsigned& b) {
  asm volatile("s_nop 1\n\tv_permlane32_swap_b32 %0, %1\n\ts_nop 1"
               : "+v"(a), "+v"(b));
}
union FRU { unsigned u[4]; bf16x8 v8; };

// build hi/lo bf16x8 frags from 8 f32 (memory order = frag elem order)
__device__ __forceinline__ void pack_hilo8(float v0, float v1, float v2, float v3,
                                           float v4, float v5, float v6, float v7,
                                           bf16x8& hi, bf16x8& lo) {
  unsigned X0 = cvt_pk_bf16(v0, v1), X1 = cvt_pk_bf16(v2, v3);
  unsigned X2 = cvt_pk_bf16(v4, v5), X3 = cvt_pk_bf16(v6, v7);
  unsigned Y0 = cvt_pk_bf16(v0 - __uint_as_float(X0 << 16), v1 - __uint_as_float(X0 & 0xffff0000u));
  unsigned Y1 = cvt_pk_bf16(v2 - __uint_as_float(X1 << 16), v3 - __uint_as_float(X1 & 0xffff0000u));
  unsigned Y2 = cvt_pk_bf16(v4 - __uint_as_float(X2 << 16), v5 - __uint_as_float(X2 & 0xffff0000u));
  unsigned Y3 = cvt_pk_bf16(v6 - __uint_as_float(X3 << 16), v7 - __uint_as_float(X3 & 0xffff0000u));
  FRU a, c;
  a.u[0] = X0; a.u[1] = X1; a.u[2] = X2; a.u[3] = X3;
  c.u[0] = Y0; c.u[1] = Y1; c.u[2] = Y2; c.u[3] = Y3;
  hi = a.v8; lo = c.v8;
}
// P regs (S^T layout) -> PV A-frag: dw0/dw2 = swap(pk(p0,p1), pk(p4,p5)); dw1/dw3 likewise
__device__ __forceinline__ void pack_pa(float p0, float p1, float p2, float p3,
                                        float p4, float p5, float p6, float p7,
                                        bf16x8& hi, bf16x8& lo) {
  unsigned X0 = cvt_pk_bf16(p0, p1), X1 = cvt_pk_bf16(p2, p3);
  unsigned X2 = cvt_pk_bf16(p4, p5), X3 = cvt_pk_bf16(p6, p7);
  unsigned Y0 = cvt_pk_bf16(p0 - __uint_as_float(X0 << 16), p1 - __uint_as_float(X0 & 0xffff0000u));
  unsigned Y1 = cvt_pk_bf16(p2 - __uint_as_float(X1 << 16), p3 - __uint_as_float(X1 & 0xffff0000u));
  unsigned Y2 = cvt_pk_bf16(p4 - __uint_as_float(X2 << 16), p5 - __uint_as_float(X2 & 0xffff0000u));
  unsigned Y3 = cvt_pk_bf16(p6 - __uint_as_float(X3 << 16), p7 - __uint_as_float(X3 & 0xffff0000u));
  pl32swap(X0, X2); pl32swap(X1, X3);
  pl32swap(Y0, Y2); pl32swap(Y1, Y3);
  FRU a, c;
  a.u[0] = X0; a.u[1] = X1; a.u[2] = X2; a.u[3] = X3;
  c.u[0] = Y0; c.u[1] = Y1; c.u[2] = Y2; c.u[3] = Y3;
  hi = a.v8; lo = c.v8;
}

// ---------------------------------------------------------------- CPB tables
__global__ __launch_bounds__(64) void k_cpb(const float* __restrict__ w1,
                                            const float* __restrict__ b1,
                                            const float* __restrict__ w2,
                                            float* __restrict__ sbt,
                                            int n_cw, float inv_p0, float inv_p1,
                                            int ts_n0, int ts_n1) {
  int row = blockIdx.x;
  int lane = threadIdx.x;
  int ih = row / n_cw, iw = row % n_cw;
  float v0 = (float)(ts_n0 + ih) * inv_p0 * 8.0f;
  float v1 = (float)(ts_n1 + iw) * inv_p1 * 8.0f;
  v0 = (v0 >= 0.f ? 1.f : -1.f) * log2f(fabsf(v0) + 1.f) * (1.f / 3.f);
  v1 = (v1 >= 0.f ? 1.f : -1.f) * log2f(fabsf(v1) + 1.f) * (1.f / 3.f);
  float a0 = 0.f, a1 = 0.f, a2 = 0.f, a3 = 0.f;
  for (int j = lane; j < 512; j += 64) {
    float h = v0 * w1[j] + v1 * w1[512 + j] + b1[j];
    h = fmaxf(h, 0.f);
    a0 += h * w2[j * 4 + 0];
    a1 += h * w2[j * 4 + 1];
    a2 += h * w2[j * 4 + 2];
    a3 += h * w2[j * 4 + 3];
  }
#pragma unroll
  for (int off = 32; off > 0; off >>= 1) {
    a0 += __shfl_down(a0, off);
    a1 += __shfl_down(a1, off);
    a2 += __shfl_down(a2, off);
    a3 += __shfl_down(a3, off);
  }
  if (lane == 0) {
    sbt[row * 4 + 0] = 16.f / (1.f + expf(-a0));
    sbt[row * 4 + 1] = 16.f / (1.f + expf(-a1));
    sbt[row * 4 + 2] = 16.f / (1.f + expf(-a2));
    sbt[row * 4 + 3] = 16.f / (1.f + expf(-a3));
  }
}

// ---------------------------------------------------------------- expand window bias to [head][q][key]
__global__ __launch_bounds__(256) void k_bias_expand(const float* __restrict__ sbt,
                                                     float* __restrict__ bias2) {
  const int q = blockIdx.x & 255, head = blockIdx.x >> 8;
  const int key = threadIdx.x;
  const int idx = ((q >> 4) - (key >> 4) + 15) * 31 + ((q & 15) - (key & 15) + 15);
  bias2[((size_t)(head * 256 + q)) * 256 + key] = sbt[idx * 4 + head];
}

// ---------------------------------------------------------------- 4x4 mean pool
__global__ __launch_bounds__(256) void k_pool(const float* __restrict__ x,
                                              float* __restrict__ pooled) {
  int blk = blockIdx.x;            // (b, gi, gj)
  int c = threadIdx.x;
  int b = blk >> 8, gi = (blk >> 4) & 15, gj = blk & 15;
  const float* xp = x + (size_t)b * 4096 * 256 + c;
  float s = 0.f;
#pragma unroll
  for (int di = 0; di < 4; di++)
#pragma unroll
    for (int dj = 0; dj < 4; dj++)
      s += xp[(size_t)((gi * 4 + di) * 64 + gj * 4 + dj) * 256];
  pooled[(size_t)blk * 256 + c] = s * 0.0625f;
}

// ---------------------------------------------------------------- f32 GEMM 64-tile (small, anchor only)
__global__ __launch_bounds__(256) void k_gemm(const float* __restrict__ A,
                                              const float* __restrict__ W,
                                              const float* __restrict__ bias,
                                              float* __restrict__ C,
                                              int M, int N, int K, int ldw) {
  __shared__ float a_s[16][64];
  __shared__ float w_s[16][64];
  const int ntg = N >> 6;
  const int mb = blockIdx.x / ntg, nb = blockIdx.x % ntg;
  const int m0 = mb << 6, n0 = nb << 6;
  const int tid = threadIdx.x;
  const int tx = tid & 15, ty = tid >> 4;
  const int ar = tid >> 2, ac4 = (tid & 3) << 2;
  const int wk = tid >> 4, wc4 = (tid & 15) << 2;
  float acc[4][4] = {};
  for (int k0 = 0; k0 < K; k0 += 16) {
    f4 av = *(const f4*)(A + (size_t)(m0 + ar) * K + k0 + ac4);
    f4 wv = *(const f4*)(W + (size_t)(k0 + wk) * ldw + n0 + wc4);
    __syncthreads();
    a_s[ac4 + 0][ar] = av[0];
    a_s[ac4 + 1][ar] = av[1];
    a_s[ac4 + 2][ar] = av[2];
    a_s[ac4 + 3][ar] = av[3];
    *(f4*)(&w_s[wk][wc4]) = wv;
    __syncthreads();
#pragma unroll
    for (int kk = 0; kk < 16; kk++) {
      f4 a4 = *(const f4*)(&a_s[kk][ty << 2]);
      f4 w4 = *(const f4*)(&w_s[kk][tx << 2]);
#pragma unroll
      for (int i = 0; i < 4; i++)
#pragma unroll
        for (int j = 0; j < 4; j++)
          acc[i][j] = fmaf(a4[i], w4[j], acc[i][j]);
    }
  }
#pragma unroll
  for (int i = 0; i < 4; i++) {
    const int row = m0 + (ty << 2) + i;
#pragma unroll
    for (int j = 0; j < 4; j++) {
      const int col = n0 + (tx << 2) + j;
      C[(size_t)row * N + col] = acc[i][j] + bias[col];
    }
  }
}

// ---------------------------------------------------------------- f32 -> bf16 hi/lo pair
__global__ __launch_bounds__(256) void k_cvt(const float* __restrict__ in,
                                             unsigned short* __restrict__ hi,
                                             unsigned short* __restrict__ lo) {
  const size_t i = ((size_t)blockIdx.x * 256 + threadIdx.x) * 8;
  f4 v0 = *(const f4*)(in + i);
  f4 v1 = *(const f4*)(in + i + 4);
  us8 h, l;
#pragma unroll
  for (int e = 0; e < 8; e++) {
    float xv = e < 4 ? v0[e] : v1[e - 4];
    unsigned short hh = bf_rne(xv);
    h[e] = hh;
    l[e] = bf_rne(xv - bf_to_f(hh));
  }
  *(us8*)(hi + i) = h;
  *(us8*)(lo + i) = l;
}

// ---------------------------------------------------------------- weight convert + transpose
__global__ __launch_bounds__(256) void k_cvt_wt(const float* __restrict__ W,
                                                unsigned short* __restrict__ hi,
                                                unsigned short* __restrict__ lo,
                                                int N) {
  const int n = blockIdx.x, k = threadIdx.x;
  float xv = W[(size_t)k * N + n];
  unsigned short hh = bf_rne(xv);
  hi[n * 256 + k] = hh;
  lo[n * 256 + k] = bf_rne(xv - bf_to_f(hh));
}

// ---------------------------------------------------------------- split-bf16 MFMA GEMM (unchanged)
__global__ __launch_bounds__(256) void k_gemm_bf16pair(
    const unsigned short* __restrict__ Ahi, const unsigned short* __restrict__ Alo,
    const unsigned short* __restrict__ Bthi, const unsigned short* __restrict__ Btlo,
    const float* __restrict__ bias, float* __restrict__ C, int M, int N) {
  __shared__ __align__(16) unsigned short ah_s[128 * 32];
  __shared__ __align__(16) unsigned short al_s[128 * 32];
  __shared__ __align__(16) unsigned short bh_s[128 * 32];
  __shared__ __align__(16) unsigned short bl_s[128 * 32];
  const int ntg = N >> 7;
  const int m0 = (blockIdx.x / ntg) << 7, n0 = (blockIdx.x % ntg) << 7;
  const int tid = threadIdx.x;
  const int w = tid >> 6, l = tid & 63;
  const int wr = w >> 1, wc = w & 1;
  const int lr = l & 15, kg = l >> 4;
  const int srow = tid >> 2;
  const int scol = (tid & 3) << 3;
  const int lds_w = w * 512;
  f32x4 acc[4][4] = {};

  for (int k0 = 0; k0 < 256; k0 += 32) {
    const size_t ga0 = (size_t)(m0 + srow) * 256 + k0 + scol;
    const size_t ga1 = (size_t)(m0 + 64 + srow) * 256 + k0 + scol;
    const size_t gb0 = (size_t)(n0 + srow) * 256 + k0 + scol;
    const size_t gb1 = (size_t)(n0 + 64 + srow) * 256 + k0 + scol;
    stage16(Ahi + ga0, ah_s + lds_w);
    stage16(Ahi + ga1, ah_s + 2048 + lds_w);
    stage16(Alo + ga0, al_s + lds_w);
    stage16(Alo + ga1, al_s + 2048 + lds_w);
    stage16(Bthi + gb0, bh_s + lds_w);
    stage16(Bthi + gb1, bh_s + 2048 + lds_w);
    stage16(Btlo + gb0, bl_s + lds_w);
    stage16(Btlo + gb1, bl_s + 2048 + lds_w);
    __syncthreads();
    bf16x8 a_h[4], a_l[4], b_h[4], b_l[4];
#pragma unroll
    for (int i = 0; i < 4; i++) {
      const int r = wr * 64 + i * 16 + lr;
      a_h[i] = *(const bf16x8*)(ah_s + r * 32 + kg * 8);
      a_l[i] = *(const bf16x8*)(al_s + r * 32 + kg * 8);
    }
#pragma unroll
    for (int j = 0; j < 4; j++) {
      const int r = wc * 64 + j * 16 + lr;
      b_h[j] = *(const bf16x8*)(bh_s + r * 32 + kg * 8);
      b_l[j] = *(const bf16x8*)(bl_s + r * 32 + kg * 8);
    }
#pragma unroll
    for (int i = 0; i < 4; i++)
#pragma unroll
      for (int j = 0; j < 4; j++) {
        acc[i][j] = __builtin_amdgcn_mfma_f32_16x16x32_bf16(a_h[i], b_h[j], acc[i][j], 0, 0, 0);
        acc[i][j] = __builtin_amdgcn_mfma_f32_16x16x32_bf16(a_h[i], b_l[j], acc[i][j], 0, 0, 0);
        acc[i][j] = __builtin_amdgcn_mfma_f32_16x16x32_bf16(a_l[i], b_h[j], acc[i][j], 0, 0, 0);
      }
    __syncthreads();
  }
#pragma unroll
  for (int j = 0; j < 4; j++) {
    const int col = n0 + wc * 64 + j * 16 + lr;
    const float bj = bias[col];
#pragma unroll
    for (int i = 0; i < 4; i++) {
      const int row0 = m0 + wr * 64 + i * 16 + kg * 4;
#pragma unroll
      for (int r = 0; r < 4; r++)
        C[(size_t)(row0 + r) * N + col] = acc[i][j][r] + bj;
    }
  }
}

// ---------------------------------------------------------------- window attention (MFMA, split-bf16)
// block = (window, head): 256 tokens x 256 keys x d=32. 4 waves, wave w owns q rows 64w..64w+63.
// Swapped QK^T (A=K rows=key, B=Q cols=q) => scores lane-local per q; fixed softmax max M=escale+16.
// K staged normalized hi/lo [256][40 pad]; V^T staged hi/lo [32][264 pad]. ~73 KB LDS, 2 blk/CU.
__global__ __launch_bounds__(256) void k_win_attn_mfma(
    const float* __restrict__ qkvw, const float* __restrict__ bias2,
    const float* __restrict__ ls, float* __restrict__ outp) {
  __shared__ __align__(16) unsigned short kh_s[256 * 40];
  __shared__ __align__(16) unsigned short kl_s[256 * 40];
  __shared__ __align__(16) unsigned short vth_s[32 * 264];
  __shared__ __align__(16) unsigned short vtl_s[32 * 264];
  const int head = blockIdx.x & 3, win = blockIdx.x >> 2;
  const int b = win >> 4, wh = (win >> 2) & 3, ww = win & 3;
  const size_t rowbase = (size_t)b * 4096 + wh * 1024 + ww * 16;
  const int tid = threadIdx.x;
  const int l = tid & 63, wv = tid >> 6;
  const int h = l >> 5, l31 = l & 31;
  const float escale = __expf(fminf(ls[head], LOGIT_MAX_F));
  const float M = escale + 16.f;

  // ---- stage normalized K (hi/lo) and transposed V (hi/lo); one key per thread
  {
    const int key = tid;
    const float* kp = qkvw + (rowbase + (key >> 4) * 64 + (key & 15)) * 384 + 128 + head * 32;
    f4 kv[8];
    float ss = 0.f;
#pragma unroll
    for (int c = 0; c < 8; c++) {
      kv[c] = *(const f4*)(kp + c * 4);
      ss += kv[c][0] * kv[c][0] + kv[c][1] * kv[c][1] + kv[c][2] * kv[c][2] + kv[c][3] * kv[c][3];
    }
    const float kinv = 1.f / fmaxf(sqrtf(ss), 1e-12f);
#pragma unroll
    for (int g = 0; g < 4; g++) {
      us8 h8, l8;
#pragma unroll
      for (int e = 0; e < 8; e++) {
        const float v = ((e < 4) ? kv[g * 2][e] : kv[g * 2 + 1][e - 4]) * kinv;
        const unsigned short hh = bf_rne(v);
        h8[e] = hh;
        l8[e] = bf_rne(v - bf_to_f(hh));
      }
      *(us8*)(kh_s + key * 40 + g * 8) = h8;
      *(us8*)(kl_s + key * 40 + g * 8) = l8;
    }
    const float* vp = kp + 128;  // V channels
#pragma unroll
    for (int c = 0; c < 8; c++) {
      f4 vvv = *(const f4*)(vp + c * 4);
#pragma unroll
      for (int e = 0; e < 4; e++) {
        const int d = c * 4 + e;
        const unsigned short hh = bf_rne(vvv[e]);
        vth_s[d * 264 + key] = hh;
        vtl_s[d * 264 + key] = bf_rne(vvv[e] - bf_to_f(hh));
      }
    }
  }

  // ---- per-lane Q fragments (pre-scaled by escale/||q||, hi/lo), B-frag layout
  bf16x8 qfh[2][2], qfl[2][2];
  int qtok[2];
#pragma unroll
  for (int qt = 0; qt < 2; qt++) {
    qtok[qt] = wv * 64 + qt * 32 + l31;
    const float* qp = qkvw + (rowbase + (qtok[qt] >> 4) * 64 + (qtok[qt] & 15)) * 384 + head * 32;
    f4 qa0 = *(const f4*)(qp + h * 8);
    f4 qa1 = *(const f4*)(qp + h * 8 + 4);
    f4 qb0 = *(const f4*)(qp + 16 + h * 8);
    f4 qb1 = *(const f4*)(qp + 16 + h * 8 + 4);
    float ssq = 0.f;
#pragma unroll
    for (int e = 0; e < 4; e++)
      ssq += qa0[e] * qa0[e] + qa1[e] * qa1[e] + qb0[e] * qb0[e] + qb1[e] * qb1[e];
    ssq += __shfl_xor(ssq, 32);
    const float qsc = escale / fmaxf(sqrtf(ssq), 1e-12f);
    pack_hilo8(qa0[0] * qsc, qa0[1] * qsc, qa0[2] * qsc, qa0[3] * qsc,
               qa1[0] * qsc, qa1[1] * qsc, qa1[2] * qsc, qa1[3] * qsc,
               qfh[qt][0], qfl[qt][0]);
    pack_hilo8(qb0[0] * qsc, qb0[1] * qsc, qb0[2] * qsc, qb0[3] * qsc,
               qb1[0] * qsc, qb1[1] * qsc, qb1[2] * qsc, qb1[3] * qsc,
               qfh[qt][1], qfl[qt][1]);
  }
  __syncthreads();

  // ---- main loop over 8 key-chunks of 32
  f32x16 o0 = {}, o1 = {};
  float rs0 = 0.f, rs1 = 0.f;
#pragma unroll 1
  for (int kt = 0; kt < 8; kt++) {
    const int kbase = (kt * 32 + l31) * 40 + h * 8;
    const bf16x8 kh0 = *(const bf16x8*)(kh_s + kbase);
    const bf16x8 kh1 = *(const bf16x8*)(kh_s + kbase + 16);
    const bf16x8 kl0 = *(const bf16x8*)(kl_s + kbase);
    const bf16x8 kl1 = *(const bf16x8*)(kl_s + kbase + 16);
    f32x16 st0 = {}, st1 = {};
    st0 = __builtin_amdgcn_mfma_f32_32x32x16_bf16(kh0, qfh[0][0], st0, 0, 0, 0);
    st0 = __builtin_amdgcn_mfma_f32_32x32x16_bf16(kh1, qfh[0][1], st0, 0, 0, 0);
    st0 = __builtin_amdgcn_mfma_f32_32x32x16_bf16(kh0, qfl[0][0], st0, 0, 0, 0);
    st0 = __builtin_amdgcn_mfma_f32_32x32x16_bf16(kh1, qfl[0][1], st0, 0, 0, 0);
    st0 = __builtin_amdgcn_mfma_f32_32x32x16_bf16(kl0, qfh[0][0], st0, 0, 0, 0);
    st0 = __builtin_amdgcn_mfma_f32_32x32x16_bf16(kl1, qfh[0][1], st0, 0, 0, 0);
    st1 = __builtin_amdgcn_mfma_f32_32x32x16_bf16(kh0, qfh[1][0], st1, 0, 0, 0);
    st1 = __builtin_amdgcn_mfma_f32_32x32x16_bf16(kh1, qfh[1][1], st1, 0, 0, 0);
    st1 = __builtin_amdgcn_mfma_f32_32x32x16_bf16(kh0, qfl[1][0], st1, 0, 0, 0);
    st1 = __builtin_amdgcn_mfma_f32_32x32x16_bf16(kh1, qfl[1][1], st1, 0, 0, 0);
    st1 = __builtin_amdgcn_mfma_f32_32x32x16_bf16(kl0, qfh[1][0], st1, 0, 0, 0);
    st1 = __builtin_amdgcn_mfma_f32_32x32x16_bf16(kl1, qfh[1][1], st1, 0, 0, 0);

    // bias + exp (lane-local softmax rows, fixed max M)
    float p0[16], p1[16];
    {
      const float* bp = bias2 + ((size_t)(head * 256 + qtok[0])) * 256 + kt * 32 + h * 4;
      f4 b0 = *(const f4*)(bp);
      f4 b1 = *(const f4*)(bp + 8);
      f4 b2 = *(const f4*)(bp + 16);
      f4 b3 = *(const f4*)(bp + 24);
      float a = 0.f;
#pragma unroll
      for (int r = 0; r < 16; r++) {
        const float bb = (r < 4) ? b0[r & 3] : (r < 8) ? b1[r & 3] : (r < 12) ? b2[r & 3] : b3[r & 3];
        const float pv = __expf(st0[r] + bb - M);
        p0[r] = pv;
        a += pv;
      }
      rs0 += a;
    }
    {
      const float* bp = bias2 + ((size_t)(head * 256 + qtok[1])) * 256 + kt * 32 + h * 4;
      f4 b0 = *(const f4*)(bp);
      f4 b1 = *(const f4*)(bp + 8);
      f4 b2 = *(const f4*)(bp + 16);
      f4 b3 = *(const f4*)(bp + 24);
      float a = 0.f;
#pragma unroll
      for (int r = 0; r < 16; r++) {
        const float bb = (r < 4) ? b0[r & 3] : (r < 8) ? b1[r & 3] : (r < 12) ? b2[r & 3] : b3[r & 3];
        const float pv = __expf(st1[r] + bb - M);
        p1[r] = pv;
        a += pv;
      }
      rs1 += a;
    }

    // PV: per 16-key step, exchange P into A-frag layout, V^T b128 reads
#pragma unroll
    for (int s = 0; s < 2; s++) {
      const int vbase = l31 * 264 + kt * 32 + s * 16 + h * 8;
      const bf16x8 vh = *(const bf16x8*)(vth_s + vbase);
      const bf16x8 vl = *(const bf16x8*)(vtl_s + vbase);
      bf16x8 pah, pal;
      if (s == 0)
        pack_pa(p0[0], p0[1], p0[2], p0[3], p0[4], p0[5], p0[6], p0[7], pah, pal);
      else
        pack_pa(p0[8], p0[9], p0[10], p0[11], p0[12], p0[13], p0[14], p0[15], pah, pal);
      o0 = __builtin_amdgcn_mfma_f32_32x32x16_bf16(pah, vh, o0, 0, 0, 0);
      o0 = __builtin_amdgcn_mfma_f32_32x32x16_bf16(pah, vl, o0, 0, 0, 0);
      o0 = __builtin_amdgcn_mfma_f32_32x32x16_bf16(pal, vh, o0, 0, 0, 0);
      if (s == 0)
        pack_pa(p1[0], p1[1], p1[2], p1[3], p1[4], p1[5], p1[6], p1[7], pah, pal);
      else
        pack_pa(p1[8], p1[9], p1[10], p1[11], p1[12], p1[13], p1[14], p1[15], pah, pal);
      o1 = __builtin_amdgcn_mfma_f32_32x32x16_bf16(pah, vh, o1, 0, 0, 0);
      o1 = __builtin_amdgcn_mfma_f32_32x32x16_bf16(pah, vl, o1, 0, 0, 0);
      o1 = __builtin_amdgcn_mfma_f32_32x32x16_bf16(pal, vh, o1, 0, 0, 0);
    }
  }

  // ---- epilogue: normalize and write (O layout: col=l31=d, rows=crow(r,h))
  const float inv0 = 1.f / fmaxf(rs0 + __shfl_xor(rs0, 32), 1e-37f);
  const float inv1 = 1.f / fmaxf(rs1 + __shfl_xor(rs1, 32), 1e-37f);
#pragma unroll
  for (int r = 0; r < 16; r++) {
    const int qrow = (r & 3) + 8 * (r >> 2) + 4 * h;
    const float iv0 = __shfl(inv0, qrow);
    const int qq0 = wv * 64 + qrow;
    outp[(rowbase + (qq0 >> 4) * 64 + (qq0 & 15)) * 256 + head * 32 + l31] = o0[r] * iv0;
    const float iv1 = __shfl(inv1, qrow);
    const int qq1 = wv * 64 + 32 + qrow;
    outp[(rowbase + (qq1 >> 4) * 64 + (qq1 & 15)) * 256 + head * 32 + l31] = o1[r] * iv1;
  }
}

// ---------------------------------------------------------------- stripe stage 1 (unchanged)
__global__ __launch_bounds__(256) void k_stripe1(const float* __restrict__ qkvs,
                                                 const float* __restrict__ anch,
                                                 const float* __restrict__ sbt,
                                                 const float* __restrict__ ls,
                                                 float* __restrict__ tbuf) {
  __shared__ float kinv_s[1024];
  __shared__ float ansc[64];
  __shared__ float bias_s[1501];
  __shared__ float mxred[64][4];
  __shared__ float rsred[64][4];
  __shared__ float opart[64][4][33];
  const int head = blockIdx.x & 3, sb = blockIdx.x >> 2;
  const int b = sb >> 2, wj = sb & 3;
  const size_t rowbase = (size_t)b * 4096 + wj * 16;
  const size_t abase = (size_t)b * 256 + wj * 4;
  const int tid = threadIdx.x;
  const int q = tid & 63, sl = tid >> 6;
  const float escale = __expf(fminf(ls[head], LOGIT_MAX_F));
  for (int tt = tid; tt < 1024; tt += 256) {
    const float* kp = qkvs + (rowbase + (tt >> 4) * 64 + (tt & 15)) * 384 + 128 + head * 32;
    float ss = 0.f;
#pragma unroll
    for (int c = 0; c < 8; c++) {
      f4 kv = *(const f4*)(kp + c * 4);
      ss += kv[0] * kv[0] + kv[1] * kv[1] + kv[2] * kv[2] + kv[3] * kv[3];
    }
    kinv_s[tt] = 1.f / fmaxf(sqrtf(ss), 1e-12f);
  }
  if (tid < 64) {
    const float* ap = anch + (abase + (tid >> 2) * 16 + (tid & 3)) * 128 + head * 32;
    float ss = 0.f;
#pragma unroll
    for (int c = 0; c < 8; c++) {
      f4 v = *(const f4*)(ap + c * 4);
      ss += v[0] * v[0] + v[1] * v[1] + v[2] * v[2] + v[3] * v[3];
    }
    ansc[tid] = 1.f / fmaxf(sqrtf(ss), 1e-12f);
  }
  for (int i = tid; i < 1501; i += 256) bias_s[i] = sbt[i * 4 + head];
  __syncthreads();

  const float* qp = anch + (abase + (q >> 2) * 16 + (q & 3)) * 128 + head * 32;
  f4 q8[8];
#pragma unroll
  for (int c = 0; c < 8; c++) q8[c] = *(const f4*)(qp + c * 4);
  const float qsc = escale * ansc[q];
  const int ah = q >> 2, aw = q & 3;

  float mx = -1e30f, rs = 0.f;
  f4 o8[8] = {};
#pragma unroll 1
  for (int cc = 0; cc < 16; cc++) {
    const int ti = sl * 16 + cc;
    const int bb = (ah - ti + 63) * 19 + aw + 15;
    const float* rowp = qkvs + (rowbase + ti * 64) * 384 + head * 32;
    float s16[16];
    float cmx = -1e30f;
#pragma unroll
    for (int tj = 0; tj < 16; tj++) {
      const float* kp = rowp + tj * 384 + 128;
      float s = 0.f;
#pragma unroll
      for (int c = 0; c < 8; c++) {
        f4 kv = *(const f4*)(kp + c * 4);
        s = fmaf(q8[c][0], kv[0], s); s = fmaf(q8[c][1], kv[1], s);
        s = fmaf(q8[c][2], kv[2], s); s = fmaf(q8[c][3], kv[3], s);
      }
      s = s * qsc * kinv_s[ti * 16 + tj] + bias_s[bb - tj];
      s16[tj] = s;
      cmx = fmaxf(cmx, s);
    }
    const float nmx = fmaxf(mx, cmx);
    const float alpha = __expf(mx - nmx);
    rs *= alpha;
#pragma unroll
    for (int c = 0; c < 8; c++) o8[c] *= alpha;
    mx = nmx;
#pragma unroll
    for (int tj = 0; tj < 16; tj++) {
      const float p = __expf(s16[tj] - mx);
      rs += p;
      const float* vp = rowp + tj * 384 + 256;
#pragma unroll
      for (int c = 0; c < 8; c++) {
        f4 vv = *(const f4*)(vp + c * 4);
        o8[c] += vv * p;
      }
    }
  }
  mxred[q][sl] = mx;
  __syncthreads();
  const float mxg = fmaxf(fmaxf(mxred[q][0], mxred[q][1]), fmaxf(mxred[q][2], mxred[q][3]));
  const float w = __expf(mx - mxg);
  rsred[q][sl] = rs * w;
#pragma unroll
  for (int c = 0; c < 8; c++) {
    opart[q][sl][c * 4 + 0] = o8[c][0] * w;
    opart[q][sl][c * 4 + 1] = o8[c][1] * w;
    opart[q][sl][c * 4 + 2] = o8[c][2] * w;
    opart[q][sl][c * 4 + 3] = o8[c][3] * w;
  }
  __syncthreads();
  {
    const int q2 = tid >> 2, cg = (tid & 3) << 3;
    const float inv = 1.f / (rsred[q2][0] + rsred[q2][1] + rsred[q2][2] + rsred[q2][3]);
    float* tp = tbuf + (size_t)blockIdx.x * 2048 + q2 * 32 + cg;
#pragma unroll
    for (int i = 0; i < 8; i++) {
      const int c = cg + i;
      tp[i] = (opart[q2][0][c] + opart[q2][1][c] + opart[q2][2][c] + opart[q2][3][c]) * inv;
    }
  }
}

// ---------------------------------------------------------------- stripe stage 2 (unchanged)
__global__ __launch_bounds__(256) void k_stripe2(const float* __restrict__ qkvs,
                                                 const float* __restrict__ anch,
                                                 const float* __restrict__ tbuf,
                                                 const float* __restrict__ sbt,
                                                 const float* __restrict__ ls,
                                                 float* __restrict__ outp) {
  __shared__ float a_s[64][32];
  __shared__ float t_s[64][32];
  __shared__ float ansc[64];
  __shared__ float bias_s[1501];
  const int head = blockIdx.x & 3, sb = blockIdx.x >> 2;
  const int b = sb >> 2, wj = sb & 3;
  const size_t rowbase = (size_t)b * 4096 + wj * 16;
  const size_t abase = (size_t)b * 256 + wj * 4;
  const int tid = threadIdx.x;
  const float escale = __expf(fminf(ls[head], LOGIT_MAX_F));
  if (tid < 64) {
    const float* ap = anch + (abase + (tid >> 2) * 16 + (tid & 3)) * 128 + head * 32;
    const float* tp = tbuf + (size_t)blockIdx.x * 2048 + tid * 32;
    float ss = 0.f;
#pragma unroll
    for (int c = 0; c < 8; c++) {
      f4 v = *(const f4*)(ap + c * 4);
      *(f4*)(&a_s[tid][c * 4]) = v;
      ss += v[0] * v[0] + v[1] * v[1] + v[2] * v[2] + v[3] * v[3];
      *(f4*)(&t_s[tid][c * 4]) = *(const f4*)(tp + c * 4);
    }
    ansc[tid] = 1.f / fmaxf(sqrtf(ss), 1e-12f);
  }
  for (int i = tid; i < 1501; i += 256) bias_s[i] = sbt[i * 4 + head];
  __syncthreads();

#pragma unroll 1
  for (int rep = 0; rep < 4; rep++) {
    const int qt = rep * 256 + tid;
    const int ti = qt >> 4, tj = qt & 15;
    const float* qp = qkvs + (rowbase + ti * 64 + tj) * 384 + head * 32;
    f4 q8[8];
    float qss = 0.f;
#pragma unroll
    for (int c = 0; c < 8; c++) {
      q8[c] = *(const f4*)(qp + c * 4);
      qss += q8[c][0] * q8[c][0] + q8[c][1] * q8[c][1] + q8[c][2] * q8[c][2] + q8[c][3] * q8[c][3];
    }
    const float qsc = escale / fmaxf(sqrtf(qss), 1e-12f);
    float sarr[64];
    float mx = -1e30f;
#pragma unroll 1
    for (int a = 0; a < 64; a++) {
      float s = 0.f;
#pragma unroll
      for (int c = 0; c < 8; c++) {
        f4 kv = *(const f4*)(&a_s[a][c * 4]);
        s = fmaf(q8[c][0], kv[0], s); s = fmaf(q8[c][1], kv[1], s);
        s = fmaf(q8[c][2], kv[2], s); s = fmaf(q8[c][3], kv[3], s);
      }
      s = s * qsc * ansc[a] + bias_s[(ti - (a >> 2) + 15) * 19 + (tj - (a & 3) + 3)];
      sarr[a] = s;
      mx = fmaxf(mx, s);
    }
    f4 o8[8] = {};
    float rs = 0.f;
#pragma unroll 1
    for (int a = 0; a < 64; a++) {
      const float p = __expf(sarr[a] - mx);
      rs += p;
#pragma unroll
      for (int c = 0; c < 8; c++) {
        f4 tv = *(const f4*)(&t_s[a][c * 4]);
        o8[c] += tv * p;
      }
    }
    const float inv = 1.f / rs;
    float* op = outp + (rowbase + ti * 64 + tj) * 256 + 128 + head * 32;
#pragma unroll
    for (int c = 0; c < 8; c++) {
      f4 v = o8[c] * inv;
      *(f4*)(op + c * 4) = v;
    }
  }
}

// ---------------------------------------------------------------- launch
extern "C" void kernel_launch(void* const* d_in, const int* in_sizes, int n_in,
                              void* d_out, int out_size, void* d_ws, size_t ws_size,
                              hipStream_t stream) {
  (void)in_sizes; (void)n_in; (void)out_size;
  const float* x        = (const float*)d_in[0];
  const float* w_qkv    = (const float*)d_in[1];
  const float* b_qkv    = (const float*)d_in[2];
  const float* w_anchor = (const float*)d_in[3];
  const float* b_anchor = (const float*)d_in[4];
  const float* ls_w     = (const float*)d_in[5];
  const float* cw1_w    = (const float*)d_in[6];
  const float* cb1_w    = (const float*)d_in[7];
  const float* cw2_w    = (const float*)d_in[8];
  const float* ls_s1    = (const float*)d_in[9];
  const float* cw1_s1   = (const float*)d_in[10];
  const float* cb1_s1   = (const float*)d_in[11];
  const float* cw2_s1   = (const float*)d_in[12];
  const float* ls_s2    = (const float*)d_in[13];
  const float* cw1_s2   = (const float*)d_in[14];
  const float* cb1_s2   = (const float*)d_in[15];
  const float* cw2_s2   = (const float*)d_in[16];
  const float* w_proj   = (const float*)d_in[17];
  const float* b_proj   = (const float*)d_in[18];
  float* out = (float*)d_out;

  // ---- adaptive chunking over batch
  const size_t fixed_bytes =
      (size_t)4096 * 256 * 4 +          // pooled
      (size_t)4096 * 128 * 4 +          // anch
      (size_t)961 * 16 + (size_t)1501 * 16 * 2 +
      (size_t)(768 + 256) * 256 * 2 * 2 +   // transposed bf16 weights hi+lo
      (size_t)4 * 256 * 256 * 4 +           // expanded window bias [head][q][key]
      64 * 256;                          // slack
  const size_t per_nb = (size_t)4096 * 384 * 4 + (size_t)16 * 2048 * 4 +
                        (size_t)4096 * 256 * 2 * 2;
  int NB = 16;
  while (NB > 1) {
    size_t need = fixed_bytes + (size_t)NB * per_nb;
    if (need <= ws_size) break;
    NB >>= 1;
  }
  const int nchunks = 16 / NB;

  char* ws = (char*)d_ws;
  size_t off = 0;
  auto take = [&](size_t bytes) {
    char* p = ws + off;
    off += (bytes + 255) & ~(size_t)255;
    return p;
  };
  float* pooled = (float*)take((size_t)4096 * 256 * 4);
  float* anch   = (float*)take((size_t)4096 * 128 * 4);
  float* sbt_w  = (float*)take((size_t)961 * 16);
  float* sbt_s1 = (float*)take((size_t)1501 * 16);
  float* sbt_s2 = (float*)take((size_t)1501 * 16);
  float* bias2w = (float*)take((size_t)4 * 256 * 256 * 4);
  unsigned short* wqh = (unsigned short*)take((size_t)768 * 256 * 2);
  unsigned short* wql = (unsigned short*)take((size_t)768 * 256 * 2);
  unsigned short* wph = (unsigned short*)take((size_t)256 * 256 * 2);
  unsigned short* wpl = (unsigned short*)take((size_t)256 * 256 * 2);
  float* tbuf   = (float*)take((size_t)NB * 16 * 2048 * 4);
  unsigned short* xhi = (unsigned short*)take((size_t)NB * 4096 * 256 * 2);
  unsigned short* xlo = (unsigned short*)take((size_t)NB * 4096 * 256 * 2);
  float* qkvh   = (float*)take((size_t)NB * 4096 * 384 * 4);

  // ---- one-time prep
  k_cpb<<<961, 64, 0, stream>>>(cw1_w, cb1_w, cw2_w, sbt_w, 31, 1.f / 15.f, 1.f / 15.f, -15, -15);
  k_cpb<<<1501, 64, 0, stream>>>(cw1_s1, cb1_s1, cw2_s1, sbt_s1, 19, 1.f / 39.f, 1.f / 9.f, -39, -9);
  k_cpb<<<1501, 64, 0, stream>>>(cw1_s2, cb1_s2, cw2_s2, sbt_s2, 19, 1.f / 39.f, 1.f / 9.f, -39, -9);
  k_bias_expand<<<1024, 256, 0, stream>>>(sbt_w, bias2w);
  k_cvt_wt<<<768, 256, 0, stream>>>(w_qkv, wqh, wql, 768);
  k_cvt_wt<<<256, 256, 0, stream>>>(w_proj, wph, wpl, 256);
  k_pool<<<4096, 256, 0, stream>>>(x, pooled);
  k_gemm<<<(4096 / 64) * 2, 256, 0, stream>>>(pooled, w_anchor, b_anchor, anch, 4096, 128, 256, 128);

  // ---- chunked over batch
  const int M = NB * 4096;
  for (int c = 0; c < nchunks; c++) {
    const float* xc = x + (size_t)c * NB * 4096 * 256;
    float* outc = out + (size_t)c * NB * 4096 * 256;
    const float* anchc = anch + (size_t)c * NB * 256 * 128;
    k_cvt<<<NB * 512, 256, 0, stream>>>(xc, xhi, xlo);
    // window half (qkv channels 0..383)
    k_gemm_bf16pair<<<(M / 128) * 3, 256, 0, stream>>>(xhi, xlo, wqh, wql, b_qkv, qkvh, M, 384);
    k_win_attn_mfma<<<NB * 64, 256, 0, stream>>>(qkvh, bias2w, ls_w, outc);
    // stripe half (qkv channels 384..767) overwrites qkvh
    k_gemm_bf16pair<<<(M / 128) * 3, 256, 0, stream>>>(xhi, xlo, wqh + 384 * 256, wql + 384 * 256,
                                                       b_qkv + 384, qkvh, M, 384);
    k_stripe1<<<NB * 16, 256, 0, stream>>>(qkvh, anchc, sbt_s1, ls_s1, tbuf);
    k_stripe2<<<NB * 16, 256, 0, stream>>>(qkvh, anchc, tbuf, sbt_s2, ls_s2, outc);
  }
  // ---- final projection (reads bf16 copy of out, writes out -> no aliasing hazard)
  for (int c = 0; c < nchunks; c++) {
    float* outc = out + (size_t)c * NB * 4096 * 256;
    k_cvt<<<NB * 512, 256, 0, stream>>>(outc, xhi, xlo);
    k_gemm_bf16pair<<<(M / 128) * 2, 256, 0, stream>>>(xhi, xlo, wph, wpl, b_proj, outc, M, 256);
  }
}

// Round 4
// 517.577 us; speedup vs baseline: 2.4480x; 1.6924x over previous
//
#include <hip/hip_runtime.h>
#include <math.h>

typedef float f4 __attribute__((ext_vector_type(4)));
typedef float f32x4 __attribute__((ext_vector_type(4)));
typedef float f32x16 __attribute__((ext_vector_type(16)));
typedef __bf16 bf16;
typedef bf16 bf16x8 __attribute__((ext_vector_type(8)));
typedef unsigned short us8 __attribute__((ext_vector_type(8)));

#define LOGIT_MAX_F 4.605170185988092f

// ---------------------------------------------------------------- bf16 helpers
__device__ __forceinline__ unsigned short bf_rne(float x) {
  unsigned u = __float_as_uint(x);
  u += 0x7fff + ((u >> 16) & 1);
  return (unsigned short)(u >> 16);
}
__device__ __forceinline__ float bf_to_f(unsigned short h) {
  return __uint_as_float((unsigned)h << 16);
}
__device__ __forceinline__ void stage16(const unsigned short* g, unsigned short* l) {
  __builtin_amdgcn_global_load_lds(
      (const __attribute__((address_space(1))) unsigned int*)g,
      (__attribute__((address_space(3))) unsigned int*)l, 16, 0, 0);
}
// packed f32x2 -> bf16x2 (RNE), no builtin on gfx950 -> inline asm
__device__ __forceinline__ unsigned cvt_pk_bf16(float a, float b) {
  unsigned r;
  asm("v_cvt_pk_bf16_f32 %0, %1, %2" : "=v"(r) : "v"(a), "v"(b));
  return r;
}
// lane i <-> lane i+32 half-exchange; s_nops guard VALU<->permlane hazards
__device__ __forceinline__ void pl32swap(unsigned& a, unsigned& b) {
  asm volatile("s_nop 1\n\tv_permlane32_swap_b32 %0, %1\n\ts_nop 1"
               : "+v"(a), "+v"(b));
}
union FRU { unsigned u[4]; bf16x8 v8; };

// build hi/lo bf16x8 frags from 8 f32 (memory order = frag elem order)
__device__ __forceinline__ void pack_hilo8(float v0, float v1, float v2, float v3,
                                           float v4, float v5, float v6, float v7,
                                           bf16x8& hi, bf16x8& lo) {
  unsigned X0 = cvt_pk_bf16(v0, v1), X1 = cvt_pk_bf16(v2, v3);
  unsigned X2 = cvt_pk_bf16(v4, v5), X3 = cvt_pk_bf16(v6, v7);
  unsigned Y0 = cvt_pk_bf16(v0 - __uint_as_float(X0 << 16), v1 - __uint_as_float(X0 & 0xffff0000u));
  unsigned Y1 = cvt_pk_bf16(v2 - __uint_as_float(X1 << 16), v3 - __uint_as_float(X1 & 0xffff0000u));
  unsigned Y2 = cvt_pk_bf16(v4 - __uint_as_float(X2 << 16), v5 - __uint_as_float(X2 & 0xffff0000u));
  unsigned Y3 = cvt_pk_bf16(v6 - __uint_as_float(X3 << 16), v7 - __uint_as_float(X3 & 0xffff0000u));
  FRU a, c;
  a.u[0] = X0; a.u[1] = X1; a.u[2] = X2; a.u[3] = X3;
  c.u[0] = Y0; c.u[1] = Y1; c.u[2] = Y2; c.u[3] = Y3;
  hi = a.v8; lo = c.v8;
}
// P regs (S^T layout, one 16-key step) -> PV A-frag (hi/lo) incl. cross-half swap
__device__ __forceinline__ void pack_pa(float p0, float p1, float p2, float p3,
                                        float p4, float p5, float p6, float p7,
                                        bf16x8& hi, bf16x8& lo) {
  unsigned X0 = cvt_pk_bf16(p0, p1), X1 = cvt_pk_bf16(p2, p3);
  unsigned X2 = cvt_pk_bf16(p4, p5), X3 = cvt_pk_bf16(p6, p7);
  unsigned Y0 = cvt_pk_bf16(p0 - __uint_as_float(X0 << 16), p1 - __uint_as_float(X0 & 0xffff0000u));
  unsigned Y1 = cvt_pk_bf16(p2 - __uint_as_float(X1 << 16), p3 - __uint_as_float(X1 & 0xffff0000u));
  unsigned Y2 = cvt_pk_bf16(p4 - __uint_as_float(X2 << 16), p5 - __uint_as_float(X2 & 0xffff0000u));
  unsigned Y3 = cvt_pk_bf16(p6 - __uint_as_float(X3 << 16), p7 - __uint_as_float(X3 & 0xffff0000u));
  pl32swap(X0, X2); pl32swap(X1, X3);
  pl32swap(Y0, Y2); pl32swap(Y1, Y3);
  FRU a, c;
  a.u[0] = X0; a.u[1] = X1; a.u[2] = X2; a.u[3] = X3;
  c.u[0] = Y0; c.u[1] = Y1; c.u[2] = Y2; c.u[3] = Y3;
  hi = a.v8; lo = c.v8;
}

// ---------------------------------------------------------------- CPB tables
__global__ __launch_bounds__(64) void k_cpb(const float* __restrict__ w1,
                                            const float* __restrict__ b1,
                                            const float* __restrict__ w2,
                                            float* __restrict__ sbt,
                                            int n_cw, float inv_p0, float inv_p1,
                                            int ts_n0, int ts_n1) {
  int row = blockIdx.x;
  int lane = threadIdx.x;
  int ih = row / n_cw, iw = row % n_cw;
  float v0 = (float)(ts_n0 + ih) * inv_p0 * 8.0f;
  float v1 = (float)(ts_n1 + iw) * inv_p1 * 8.0f;
  v0 = (v0 >= 0.f ? 1.f : -1.f) * log2f(fabsf(v0) + 1.f) * (1.f / 3.f);
  v1 = (v1 >= 0.f ? 1.f : -1.f) * log2f(fabsf(v1) + 1.f) * (1.f / 3.f);
  float a0 = 0.f, a1 = 0.f, a2 = 0.f, a3 = 0.f;
  for (int j = lane; j < 512; j += 64) {
    float h = v0 * w1[j] + v1 * w1[512 + j] + b1[j];
    h = fmaxf(h, 0.f);
    a0 += h * w2[j * 4 + 0];
    a1 += h * w2[j * 4 + 1];
    a2 += h * w2[j * 4 + 2];
    a3 += h * w2[j * 4 + 3];
  }
#pragma unroll
  for (int off = 32; off > 0; off >>= 1) {
    a0 += __shfl_down(a0, off);
    a1 += __shfl_down(a1, off);
    a2 += __shfl_down(a2, off);
    a3 += __shfl_down(a3, off);
  }
  if (lane == 0) {
    sbt[row * 4 + 0] = 16.f / (1.f + expf(-a0));
    sbt[row * 4 + 1] = 16.f / (1.f + expf(-a1));
    sbt[row * 4 + 2] = 16.f / (1.f + expf(-a2));
    sbt[row * 4 + 3] = 16.f / (1.f + expf(-a3));
  }
}

// ---------------------------------------------------------------- expand window bias to [head][q][key]
__global__ __launch_bounds__(256) void k_bias_expand(const float* __restrict__ sbt,
                                                     float* __restrict__ bias2) {
  const int q = blockIdx.x & 255, head = blockIdx.x >> 8;
  const int key = threadIdx.x;
  const int idx = ((q >> 4) - (key >> 4) + 15) * 31 + ((q & 15) - (key & 15) + 15);
  bias2[((size_t)(head * 256 + q)) * 256 + key] = sbt[idx * 4 + head];
}

// ---------------------------------------------------------------- expand stripe biases
// bias1x[head][a(64)][key(1024)]  (anchor->window, stage 1)
__global__ __launch_bounds__(256) void k_bias1x(const float* __restrict__ sbt,
                                                float* __restrict__ bx) {
  const int head = blockIdx.x >> 6, a = blockIdx.x & 63;
#pragma unroll
  for (int k4 = 0; k4 < 4; k4++) {
    const int key = threadIdx.x + k4 * 256;
    const int idx = ((a >> 2) - (key >> 4) + 63) * 19 + (a & 3) - (key & 15) + 15;
    bx[((size_t)(head * 64 + a)) * 1024 + key] = sbt[idx * 4 + head];
  }
}
// bias2x[head][q(1024)][a(64)]  (window->anchor, stage 2)
__global__ __launch_bounds__(64) void k_bias2x(const float* __restrict__ sbt,
                                               float* __restrict__ bx) {
  const int head = blockIdx.x >> 10, q = blockIdx.x & 1023;
  const int a = threadIdx.x;
  const int idx = ((q >> 4) - (a >> 2) + 15) * 19 + (q & 15) - (a & 3) + 3;
  bx[((size_t)(head * 1024 + q)) * 64 + a] = sbt[idx * 4 + head];
}

// ---------------------------------------------------------------- 4x4 mean pool
__global__ __launch_bounds__(256) void k_pool(const float* __restrict__ x,
                                              float* __restrict__ pooled) {
  int blk = blockIdx.x;            // (b, gi, gj)
  int c = threadIdx.x;
  int b = blk >> 8, gi = (blk >> 4) & 15, gj = blk & 15;
  const float* xp = x + (size_t)b * 4096 * 256 + c;
  float s = 0.f;
#pragma unroll
  for (int di = 0; di < 4; di++)
#pragma unroll
    for (int dj = 0; dj < 4; dj++)
      s += xp[(size_t)((gi * 4 + di) * 64 + gj * 4 + dj) * 256];
  pooled[(size_t)blk * 256 + c] = s * 0.0625f;
}

// ---------------------------------------------------------------- f32 GEMM 64-tile (small, anchor only)
__global__ __launch_bounds__(256) void k_gemm(const float* __restrict__ A,
                                              const float* __restrict__ W,
                                              const float* __restrict__ bias,
                                              float* __restrict__ C,
                                              int M, int N, int K, int ldw) {
  __shared__ float a_s[16][64];
  __shared__ float w_s[16][64];
  const int ntg = N >> 6;
  const int mb = blockIdx.x / ntg, nb = blockIdx.x % ntg;
  const int m0 = mb << 6, n0 = nb << 6;
  const int tid = threadIdx.x;
  const int tx = tid & 15, ty = tid >> 4;
  const int ar = tid >> 2, ac4 = (tid & 3) << 2;
  const int wk = tid >> 4, wc4 = (tid & 15) << 2;
  float acc[4][4] = {};
  for (int k0 = 0; k0 < K; k0 += 16) {
    f4 av = *(const f4*)(A + (size_t)(m0 + ar) * K + k0 + ac4);
    f4 wv = *(const f4*)(W + (size_t)(k0 + wk) * ldw + n0 + wc4);
    __syncthreads();
    a_s[ac4 + 0][ar] = av[0];
    a_s[ac4 + 1][ar] = av[1];
    a_s[ac4 + 2][ar] = av[2];
    a_s[ac4 + 3][ar] = av[3];
    *(f4*)(&w_s[wk][wc4]) = wv;
    __syncthreads();
#pragma unroll
    for (int kk = 0; kk < 16; kk++) {
      f4 a4 = *(const f4*)(&a_s[kk][ty << 2]);
      f4 w4 = *(const f4*)(&w_s[kk][tx << 2]);
#pragma unroll
      for (int i = 0; i < 4; i++)
#pragma unroll
        for (int j = 0; j < 4; j++)
          acc[i][j] = fmaf(a4[i], w4[j], acc[i][j]);
    }
  }
#pragma unroll
  for (int i = 0; i < 4; i++) {
    const int row = m0 + (ty << 2) + i;
#pragma unroll
    for (int j = 0; j < 4; j++) {
      const int col = n0 + (tx << 2) + j;
      C[(size_t)row * N + col] = acc[i][j] + bias[col];
    }
  }
}

// ---------------------------------------------------------------- f32 -> bf16 hi/lo pair
__global__ __launch_bounds__(256) void k_cvt(const float* __restrict__ in,
                                             unsigned short* __restrict__ hi,
                                             unsigned short* __restrict__ lo) {
  const size_t i = ((size_t)blockIdx.x * 256 + threadIdx.x) * 8;
  f4 v0 = *(const f4*)(in + i);
  f4 v1 = *(const f4*)(in + i + 4);
  us8 h, l;
#pragma unroll
  for (int e = 0; e < 8; e++) {
    float xv = e < 4 ? v0[e] : v1[e - 4];
    unsigned short hh = bf_rne(xv);
    h[e] = hh;
    l[e] = bf_rne(xv - bf_to_f(hh));
  }
  *(us8*)(hi + i) = h;
  *(us8*)(lo + i) = l;
}

// ---------------------------------------------------------------- weight convert + transpose
__global__ __launch_bounds__(256) void k_cvt_wt(const float* __restrict__ W,
                                                unsigned short* __restrict__ hi,
                                                unsigned short* __restrict__ lo,
                                                int N) {
  const int n = blockIdx.x, k = threadIdx.x;
  float xv = W[(size_t)k * N + n];
  unsigned short hh = bf_rne(xv);
  hi[n * 256 + k] = hh;
  lo[n * 256 + k] = bf_rne(xv - bf_to_f(hh));
}

// ---------------------------------------------------------------- split-bf16 MFMA GEMM
__global__ __launch_bounds__(256) void k_gemm_bf16pair(
    const unsigned short* __restrict__ Ahi, const unsigned short* __restrict__ Alo,
    const unsigned short* __restrict__ Bthi, const unsigned short* __restrict__ Btlo,
    const float* __restrict__ bias, float* __restrict__ C, int M, int N) {
  __shared__ __align__(16) unsigned short ah_s[128 * 32];
  __shared__ __align__(16) unsigned short al_s[128 * 32];
  __shared__ __align__(16) unsigned short bh_s[128 * 32];
  __shared__ __align__(16) unsigned short bl_s[128 * 32];
  const int ntg = N >> 7;
  const int m0 = (blockIdx.x / ntg) << 7, n0 = (blockIdx.x % ntg) << 7;
  const int tid = threadIdx.x;
  const int w = tid >> 6, l = tid & 63;
  const int wr = w >> 1, wc = w & 1;
  const int lr = l & 15, kg = l >> 4;
  const int srow = tid >> 2;
  const int scol = (tid & 3) << 3;
  const int lds_w = w * 512;
  f32x4 acc[4][4] = {};

  for (int k0 = 0; k0 < 256; k0 += 32) {
    const size_t ga0 = (size_t)(m0 + srow) * 256 + k0 + scol;
    const size_t ga1 = (size_t)(m0 + 64 + srow) * 256 + k0 + scol;
    const size_t gb0 = (size_t)(n0 + srow) * 256 + k0 + scol;
    const size_t gb1 = (size_t)(n0 + 64 + srow) * 256 + k0 + scol;
    stage16(Ahi + ga0, ah_s + lds_w);
    stage16(Ahi + ga1, ah_s + 2048 + lds_w);
    stage16(Alo + ga0, al_s + lds_w);
    stage16(Alo + ga1, al_s + 2048 + lds_w);
    stage16(Bthi + gb0, bh_s + lds_w);
    stage16(Bthi + gb1, bh_s + 2048 + lds_w);
    stage16(Btlo + gb0, bl_s + lds_w);
    stage16(Btlo + gb1, bl_s + 2048 + lds_w);
    __syncthreads();
    bf16x8 a_h[4], a_l[4], b_h[4], b_l[4];
#pragma unroll
    for (int i = 0; i < 4; i++) {
      const int r = wr * 64 + i * 16 + lr;
      a_h[i] = *(const bf16x8*)(ah_s + r * 32 + kg * 8);
      a_l[i] = *(const bf16x8*)(al_s + r * 32 + kg * 8);
    }
#pragma unroll
    for (int j = 0; j < 4; j++) {
      const int r = wc * 64 + j * 16 + lr;
      b_h[j] = *(const bf16x8*)(bh_s + r * 32 + kg * 8);
      b_l[j] = *(const bf16x8*)(bl_s + r * 32 + kg * 8);
    }
#pragma unroll
    for (int i = 0; i < 4; i++)
#pragma unroll
      for (int j = 0; j < 4; j++) {
        acc[i][j] = __builtin_amdgcn_mfma_f32_16x16x32_bf16(a_h[i], b_h[j], acc[i][j], 0, 0, 0);
        acc[i][j] = __builtin_amdgcn_mfma_f32_16x16x32_bf16(a_h[i], b_l[j], acc[i][j], 0, 0, 0);
        acc[i][j] = __builtin_amdgcn_mfma_f32_16x16x32_bf16(a_l[i], b_h[j], acc[i][j], 0, 0, 0);
      }
    __syncthreads();
  }
#pragma unroll
  for (int j = 0; j < 4; j++) {
    const int col = n0 + wc * 64 + j * 16 + lr;
    const float bj = bias[col];
#pragma unroll
    for (int i = 0; i < 4; i++) {
      const int row0 = m0 + wr * 64 + i * 16 + kg * 4;
#pragma unroll
      for (int r = 0; r < 4; r++)
        C[(size_t)(row0 + r) * N + col] = acc[i][j][r] + bj;
    }
  }
}

// ---------------------------------------------------------------- window attention (MFMA, unchanged)
__global__ __launch_bounds__(256) void k_win_attn_mfma(
    const float* __restrict__ qkvw, const float* __restrict__ bias2,
    const float* __restrict__ ls, float* __restrict__ outp) {
  __shared__ __align__(16) unsigned short kh_s[256 * 40];
  __shared__ __align__(16) unsigned short kl_s[256 * 40];
  __shared__ __align__(16) unsigned short vth_s[32 * 264];
  __shared__ __align__(16) unsigned short vtl_s[32 * 264];
  const int head = blockIdx.x & 3, win = blockIdx.x >> 2;
  const int b = win >> 4, wh = (win >> 2) & 3, ww = win & 3;
  const size_t rowbase = (size_t)b * 4096 + wh * 1024 + ww * 16;
  const int tid = threadIdx.x;
  const int l = tid & 63, wv = tid >> 6;
  const int h = l >> 5, l31 = l & 31;
  const float escale = __expf(fminf(ls[head], LOGIT_MAX_F));
  const float M = escale + 16.f;

  {
    const int key = tid;
    const float* kp = qkvw + (rowbase + (key >> 4) * 64 + (key & 15)) * 384 + 128 + head * 32;
    f4 kv[8];
    float ss = 0.f;
#pragma unroll
    for (int c = 0; c < 8; c++) {
      kv[c] = *(const f4*)(kp + c * 4);
      ss += kv[c][0] * kv[c][0] + kv[c][1] * kv[c][1] + kv[c][2] * kv[c][2] + kv[c][3] * kv[c][3];
    }
    const float kinv = 1.f / fmaxf(sqrtf(ss), 1e-12f);
#pragma unroll
    for (int g = 0; g < 4; g++) {
      us8 h8, l8;
#pragma unroll
      for (int e = 0; e < 8; e++) {
        const float v = ((e < 4) ? kv[g * 2][e] : kv[g * 2 + 1][e - 4]) * kinv;
        const unsigned short hh = bf_rne(v);
        h8[e] = hh;
        l8[e] = bf_rne(v - bf_to_f(hh));
      }
      *(us8*)(kh_s + key * 40 + g * 8) = h8;
      *(us8*)(kl_s + key * 40 + g * 8) = l8;
    }
    const float* vp = kp + 128;
#pragma unroll
    for (int c = 0; c < 8; c++) {
      f4 vvv = *(const f4*)(vp + c * 4);
#pragma unroll
      for (int e = 0; e < 4; e++) {
        const int d = c * 4 + e;
        const unsigned short hh = bf_rne(vvv[e]);
        vth_s[d * 264 + key] = hh;
        vtl_s[d * 264 + key] = bf_rne(vvv[e] - bf_to_f(hh));
      }
    }
  }

  bf16x8 qfh[2][2], qfl[2][2];
  int qtok[2];
#pragma unroll
  for (int qt = 0; qt < 2; qt++) {
    qtok[qt] = wv * 64 + qt * 32 + l31;
    const float* qp = qkvw + (rowbase + (qtok[qt] >> 4) * 64 + (qtok[qt] & 15)) * 384 + head * 32;
    f4 qa0 = *(const f4*)(qp + h * 8);
    f4 qa1 = *(const f4*)(qp + h * 8 + 4);
    f4 qb0 = *(const f4*)(qp + 16 + h * 8);
    f4 qb1 = *(const f4*)(qp + 16 + h * 8 + 4);
    float ssq = 0.f;
#pragma unroll
    for (int e = 0; e < 4; e++)
      ssq += qa0[e] * qa0[e] + qa1[e] * qa1[e] + qb0[e] * qb0[e] + qb1[e] * qb1[e];
    ssq += __shfl_xor(ssq, 32);
    const float qsc = escale / fmaxf(sqrtf(ssq), 1e-12f);
    pack_hilo8(qa0[0] * qsc, qa0[1] * qsc, qa0[2] * qsc, qa0[3] * qsc,
               qa1[0] * qsc, qa1[1] * qsc, qa1[2] * qsc, qa1[3] * qsc,
               qfh[qt][0], qfl[qt][0]);
    pack_hilo8(qb0[0] * qsc, qb0[1] * qsc, qb0[2] * qsc, qb0[3] * qsc,
               qb1[0] * qsc, qb1[1] * qsc, qb1[2] * qsc, qb1[3] * qsc,
               qfh[qt][1], qfl[qt][1]);
  }
  __syncthreads();

  f32x16 o0 = {}, o1 = {};
  float rs0 = 0.f, rs1 = 0.f;
#pragma unroll 1
  for (int kt = 0; kt < 8; kt++) {
    const int kbase = (kt * 32 + l31) * 40 + h * 8;
    const bf16x8 kh0 = *(const bf16x8*)(kh_s + kbase);
    const bf16x8 kh1 = *(const bf16x8*)(kh_s + kbase + 16);
    const bf16x8 kl0 = *(const bf16x8*)(kl_s + kbase);
    const bf16x8 kl1 = *(const bf16x8*)(kl_s + kbase + 16);
    f32x16 st0 = {}, st1 = {};
    st0 = __builtin_amdgcn_mfma_f32_32x32x16_bf16(kh0, qfh[0][0], st0, 0, 0, 0);
    st0 = __builtin_amdgcn_mfma_f32_32x32x16_bf16(kh1, qfh[0][1], st0, 0, 0, 0);
    st0 = __builtin_amdgcn_mfma_f32_32x32x16_bf16(kh0, qfl[0][0], st0, 0, 0, 0);
    st0 = __builtin_amdgcn_mfma_f32_32x32x16_bf16(kh1, qfl[0][1], st0, 0, 0, 0);
    st0 = __builtin_amdgcn_mfma_f32_32x32x16_bf16(kl0, qfh[0][0], st0, 0, 0, 0);
    st0 = __builtin_amdgcn_mfma_f32_32x32x16_bf16(kl1, qfh[0][1], st0, 0, 0, 0);
    st1 = __builtin_amdgcn_mfma_f32_32x32x16_bf16(kh0, qfh[1][0], st1, 0, 0, 0);
    st1 = __builtin_amdgcn_mfma_f32_32x32x16_bf16(kh1, qfh[1][1], st1, 0, 0, 0);
    st1 = __builtin_amdgcn_mfma_f32_32x32x16_bf16(kh0, qfl[1][0], st1, 0, 0, 0);
    st1 = __builtin_amdgcn_mfma_f32_32x32x16_bf16(kh1, qfl[1][1], st1, 0, 0, 0);
    st1 = __builtin_amdgcn_mfma_f32_32x32x16_bf16(kl0, qfh[1][0], st1, 0, 0, 0);
    st1 = __builtin_amdgcn_mfma_f32_32x32x16_bf16(kl1, qfh[1][1], st1, 0, 0, 0);

    float p0[16], p1[16];
    {
      const float* bp = bias2 + ((size_t)(head * 256 + qtok[0])) * 256 + kt * 32 + h * 4;
      f4 b0 = *(const f4*)(bp);
      f4 b1 = *(const f4*)(bp + 8);
      f4 b2 = *(const f4*)(bp + 16);
      f4 b3 = *(const f4*)(bp + 24);
      float a = 0.f;
#pragma unroll
      for (int r = 0; r < 16; r++) {
        const float bb = (r < 4) ? b0[r & 3] : (r < 8) ? b1[r & 3] : (r < 12) ? b2[r & 3] : b3[r & 3];
        const float pv = __expf(st0[r] + bb - M);
        p0[r] = pv;
        a += pv;
      }
      rs0 += a;
    }
    {
      const float* bp = bias2 + ((size_t)(head * 256 + qtok[1])) * 256 + kt * 32 + h * 4;
      f4 b0 = *(const f4*)(bp);
      f4 b1 = *(const f4*)(bp + 8);
      f4 b2 = *(const f4*)(bp + 16);
      f4 b3 = *(const f4*)(bp + 24);
      float a = 0.f;
#pragma unroll
      for (int r = 0; r < 16; r++) {
        const float bb = (r < 4) ? b0[r & 3] : (r < 8) ? b1[r & 3] : (r < 12) ? b2[r & 3] : b3[r & 3];
        const float pv = __expf(st1[r] + bb - M);
        p1[r] = pv;
        a += pv;
      }
      rs1 += a;
    }

#pragma unroll
    for (int s = 0; s < 2; s++) {
      const int vbase = l31 * 264 + kt * 32 + s * 16 + h * 8;
      const bf16x8 vh = *(const bf16x8*)(vth_s + vbase);
      const bf16x8 vl = *(const bf16x8*)(vtl_s + vbase);
      bf16x8 pah, pal;
      if (s == 0)
        pack_pa(p0[0], p0[1], p0[2], p0[3], p0[4], p0[5], p0[6], p0[7], pah, pal);
      else
        pack_pa(p0[8], p0[9], p0[10], p0[11], p0[12], p0[13], p0[14], p0[15], pah, pal);
      o0 = __builtin_amdgcn_mfma_f32_32x32x16_bf16(pah, vh, o0, 0, 0, 0);
      o0 = __builtin_amdgcn_mfma_f32_32x32x16_bf16(pah, vl, o0, 0, 0, 0);
      o0 = __builtin_amdgcn_mfma_f32_32x32x16_bf16(pal, vh, o0, 0, 0, 0);
      if (s == 0)
        pack_pa(p1[0], p1[1], p1[2], p1[3], p1[4], p1[5], p1[6], p1[7], pah, pal);
      else
        pack_pa(p1[8], p1[9], p1[10], p1[11], p1[12], p1[13], p1[14], p1[15], pah, pal);
      o1 = __builtin_amdgcn_mfma_f32_32x32x16_bf16(pah, vh, o1, 0, 0, 0);
      o1 = __builtin_amdgcn_mfma_f32_32x32x16_bf16(pah, vl, o1, 0, 0, 0);
      o1 = __builtin_amdgcn_mfma_f32_32x32x16_bf16(pal, vh, o1, 0, 0, 0);
    }
  }

  const float inv0 = 1.f / fmaxf(rs0 + __shfl_xor(rs0, 32), 1e-37f);
  const float inv1 = 1.f / fmaxf(rs1 + __shfl_xor(rs1, 32), 1e-37f);
#pragma unroll
  for (int r = 0; r < 16; r++) {
    const int qrow = (r & 3) + 8 * (r >> 2) + 4 * h;
    const float iv0 = __shfl(inv0, qrow);
    const int qq0 = wv * 64 + qrow;
    outp[(rowbase + (qq0 >> 4) * 64 + (qq0 & 15)) * 256 + head * 32 + l31] = o0[r] * iv0;
    const float iv1 = __shfl(inv1, qrow);
    const int qq1 = wv * 64 + 32 + qrow;
    outp[(rowbase + (qq1 >> 4) * 64 + (qq1 & 15)) * 256 + head * 32 + l31] = o1[r] * iv1;
  }
}

// ---------------------------------------------------------------- stripe stage 1 (MFMA)
// block = (b, wj, head): 64 anchors (q) x 1024 keys. 4 waves, wave owns 256 keys.
// K/V loaded global->reg, split-bf16; fixed softmax max; cross-wave LDS reduce.
__global__ __launch_bounds__(256) void k_stripe1_mfma(
    const float* __restrict__ qkvs, const float* __restrict__ anch,
    const float* __restrict__ bias1x, const float* __restrict__ ls,
    float* __restrict__ tbuf) {
  __shared__ float opart[4][64][33];
  __shared__ float rsp[4][64];
  const int head = blockIdx.x & 3, sb = blockIdx.x >> 2;
  const int b = sb >> 2, wj = sb & 3;
  const size_t rowbase = (size_t)b * 4096 + wj * 16;
  const size_t abase = (size_t)b * 256 + wj * 4;
  const int tid = threadIdx.x;
  const int l = tid & 63, wv = tid >> 6;
  const int h = l >> 5, l31 = l & 31;
  const float escale = __expf(fminf(ls[head], LOGIT_MAX_F));
  const float M = escale + 16.f;

  // anchor Q frags (B operand), 2 groups of 32, scaled escale/||a||
  bf16x8 qfh[2][2], qfl[2][2];
#pragma unroll
  for (int g = 0; g < 2; g++) {
    const int a = g * 32 + l31;
    const float* ap = anch + (abase + (a >> 2) * 16 + (a & 3)) * 128 + head * 32;
    f4 qa0 = *(const f4*)(ap + h * 8);
    f4 qa1 = *(const f4*)(ap + h * 8 + 4);
    f4 qb0 = *(const f4*)(ap + 16 + h * 8);
    f4 qb1 = *(const f4*)(ap + 16 + h * 8 + 4);
    float ss = 0.f;
#pragma unroll
    for (int e = 0; e < 4; e++)
      ss += qa0[e] * qa0[e] + qa1[e] * qa1[e] + qb0[e] * qb0[e] + qb1[e] * qb1[e];
    ss += __shfl_xor(ss, 32);
    const float qsc = escale / fmaxf(sqrtf(ss), 1e-12f);
    pack_hilo8(qa0[0] * qsc, qa0[1] * qsc, qa0[2] * qsc, qa0[3] * qsc,
               qa1[0] * qsc, qa1[1] * qsc, qa1[2] * qsc, qa1[3] * qsc,
               qfh[g][0], qfl[g][0]);
    pack_hilo8(qb0[0] * qsc, qb0[1] * qsc, qb0[2] * qsc, qb0[3] * qsc,
               qb1[0] * qsc, qb1[1] * qsc, qb1[2] * qsc, qb1[3] * qsc,
               qfh[g][1], qfl[g][1]);
  }

  f32x16 o0 = {}, o1 = {};
  float rs0 = 0.f, rs1 = 0.f;
#pragma unroll 1
  for (int kt = 0; kt < 8; kt++) {
    // K row for this lane: key = wv*256 + kt*32 + l31, normalized, A-frag dims h*8 pattern
    const int key = wv * 256 + kt * 32 + l31;
    const float* kp = qkvs + (rowbase + (key >> 4) * 64 + (key & 15)) * 384 + 128 + head * 32;
    f4 ka0 = *(const f4*)(kp + h * 8);
    f4 ka1 = *(const f4*)(kp + h * 8 + 4);
    f4 kb0 = *(const f4*)(kp + 16 + h * 8);
    f4 kb1 = *(const f4*)(kp + 16 + h * 8 + 4);
    float ss = 0.f;
#pragma unroll
    for (int e = 0; e < 4; e++)
      ss += ka0[e] * ka0[e] + ka1[e] * ka1[e] + kb0[e] * kb0[e] + kb1[e] * kb1[e];
    ss += __shfl_xor(ss, 32);
    const float kinv = 1.f / fmaxf(sqrtf(ss), 1e-12f);
    bf16x8 kh0, kl0, kh1, kl1;
    pack_hilo8(ka0[0] * kinv, ka0[1] * kinv, ka0[2] * kinv, ka0[3] * kinv,
               ka1[0] * kinv, ka1[1] * kinv, ka1[2] * kinv, ka1[3] * kinv, kh0, kl0);
    pack_hilo8(kb0[0] * kinv, kb0[1] * kinv, kb0[2] * kinv, kb0[3] * kinv,
               kb1[0] * kinv, kb1[1] * kinv, kb1[2] * kinv, kb1[3] * kinv, kh1, kl1);

    f32x16 st0 = {}, st1 = {};
    st0 = __builtin_amdgcn_mfma_f32_32x32x16_bf16(kh0, qfh[0][0], st0, 0, 0, 0);
    st0 = __builtin_amdgcn_mfma_f32_32x32x16_bf16(kh1, qfh[0][1], st0, 0, 0, 0);
    st0 = __builtin_amdgcn_mfma_f32_32x32x16_bf16(kh0, qfl[0][0], st0, 0, 0, 0);
    st0 = __builtin_amdgcn_mfma_f32_32x32x16_bf16(kh1, qfl[0][1], st0, 0, 0, 0);
    st0 = __builtin_amdgcn_mfma_f32_32x32x16_bf16(kl0, qfh[0][0], st0, 0, 0, 0);
    st0 = __builtin_amdgcn_mfma_f32_32x32x16_bf16(kl1, qfh[0][1], st0, 0, 0, 0);
    st1 = __builtin_amdgcn_mfma_f32_32x32x16_bf16(kh0, qfh[1][0], st1, 0, 0, 0);
    st1 = __builtin_amdgcn_mfma_f32_32x32x16_bf16(kh1, qfh[1][1], st1, 0, 0, 0);
    st1 = __builtin_amdgcn_mfma_f32_32x32x16_bf16(kh0, qfl[1][0], st1, 0, 0, 0);
    st1 = __builtin_amdgcn_mfma_f32_32x32x16_bf16(kh1, qfl[1][1], st1, 0, 0, 0);
    st1 = __builtin_amdgcn_mfma_f32_32x32x16_bf16(kl0, qfh[1][0], st1, 0, 0, 0);
    st1 = __builtin_amdgcn_mfma_f32_32x32x16_bf16(kl1, qfh[1][1], st1, 0, 0, 0);

    float p0[16], p1[16];
    {  // q = l31 (group 0): scores lane-local, keys crow(r,h) within chunk
      const float* bp = bias1x + ((size_t)(head * 64 + l31)) * 1024 + wv * 256 + kt * 32 + h * 4;
      f4 b0 = *(const f4*)(bp);
      f4 b1 = *(const f4*)(bp + 8);
      f4 b2 = *(const f4*)(bp + 16);
      f4 b3 = *(const f4*)(bp + 24);
      float a = 0.f;
#pragma unroll
      for (int r = 0; r < 16; r++) {
        const float bb = (r < 4) ? b0[r & 3] : (r < 8) ? b1[r & 3] : (r < 12) ? b2[r & 3] : b3[r & 3];
        const float pv = __expf(st0[r] + bb - M);
        p0[r] = pv;
        a += pv;
      }
      rs0 += a;
    }
    {
      const float* bp = bias1x + ((size_t)(head * 64 + 32 + l31)) * 1024 + wv * 256 + kt * 32 + h * 4;
      f4 b0 = *(const f4*)(bp);
      f4 b1 = *(const f4*)(bp + 8);
      f4 b2 = *(const f4*)(bp + 16);
      f4 b3 = *(const f4*)(bp + 24);
      float a = 0.f;
#pragma unroll
      for (int r = 0; r < 16; r++) {
        const float bb = (r < 4) ? b0[r & 3] : (r < 8) ? b1[r & 3] : (r < 12) ? b2[r & 3] : b3[r & 3];
        const float pv = __expf(st1[r] + bb - M);
        p1[r] = pv;
        a += pv;
      }
      rs1 += a;
    }

#pragma unroll
    for (int s = 0; s < 2; s++) {
      // V B-frag: lane needs V[key = base + s*16 + h*8 + e][d = l31]
      const int vrow0 = (wv * 256 + kt * 32 + s * 16) >> 4;  // token row group (16-aligned)
      const float* rowp = qkvs + (rowbase + (size_t)vrow0 * 64) * 384 + 256 + head * 32 + l31;
      float v8[8];
#pragma unroll
      for (int e = 0; e < 8; e++) v8[e] = rowp[(size_t)(h * 8 + e) * 384];
      bf16x8 vh, vl;
      pack_hilo8(v8[0], v8[1], v8[2], v8[3], v8[4], v8[5], v8[6], v8[7], vh, vl);
      bf16x8 pah, pal;
      if (s == 0)
        pack_pa(p0[0], p0[1], p0[2], p0[3], p0[4], p0[5], p0[6], p0[7], pah, pal);
      else
        pack_pa(p0[8], p0[9], p0[10], p0[11], p0[12], p0[13], p0[14], p0[15], pah, pal);
      o0 = __builtin_amdgcn_mfma_f32_32x32x16_bf16(pah, vh, o0, 0, 0, 0);
      o0 = __builtin_amdgcn_mfma_f32_32x32x16_bf16(pah, vl, o0, 0, 0, 0);
      o0 = __builtin_amdgcn_mfma_f32_32x32x16_bf16(pal, vh, o0, 0, 0, 0);
      if (s == 0)
        pack_pa(p1[0], p1[1], p1[2], p1[3], p1[4], p1[5], p1[6], p1[7], pah, pal);
      else
        pack_pa(p1[8], p1[9], p1[10], p1[11], p1[12], p1[13], p1[14], p1[15], pah, pal);
      o1 = __builtin_amdgcn_mfma_f32_32x32x16_bf16(pah, vh, o1, 0, 0, 0);
      o1 = __builtin_amdgcn_mfma_f32_32x32x16_bf16(pah, vl, o1, 0, 0, 0);
      o1 = __builtin_amdgcn_mfma_f32_32x32x16_bf16(pal, vh, o1, 0, 0, 0);
    }
  }

  rs0 += __shfl_xor(rs0, 32);
  rs1 += __shfl_xor(rs1, 32);
  if (h == 0) {
    rsp[wv][l31] = rs0;
    rsp[wv][32 + l31] = rs1;
  }
#pragma unroll
  for (int r = 0; r < 16; r++) {
    const int qr = (r & 3) + 8 * (r >> 2) + 4 * h;
    opart[wv][qr][l31] = o0[r];
    opart[wv][32 + qr][l31] = o1[r];
  }
  __syncthreads();
  {
    const int q = tid >> 2, d0 = (tid & 3) * 8;
    const float inv = 1.f / (rsp[0][q] + rsp[1][q] + rsp[2][q] + rsp[3][q]);
    float* tp = tbuf + (size_t)blockIdx.x * 2048 + q * 32 + d0;
#pragma unroll
    for (int i = 0; i < 8; i++) {
      const int d = d0 + i;
      tp[i] = (opart[0][q][d] + opart[1][q][d] + opart[2][q][d] + opart[3][q][d]) * inv;
    }
  }
}

// ---------------------------------------------------------------- stripe stage 2 (MFMA)
// block = (b, wj, head): 1024 q x 64 anchors, values = t. Wave owns 256 q (8 groups of 32).
// Anchor A-frags + T B-frags built once per wave and held in registers.
__global__ __launch_bounds__(256) void k_stripe2_mfma(
    const float* __restrict__ qkvs, const float* __restrict__ anch,
    const float* __restrict__ tbuf, const float* __restrict__ bias2x,
    const float* __restrict__ ls, float* __restrict__ outp) {
  __shared__ float t_s[2048];
  const int head = blockIdx.x & 3, sb = blockIdx.x >> 2;
  const int b = sb >> 2, wj = sb & 3;
  const size_t rowbase = (size_t)b * 4096 + wj * 16;
  const size_t abase = (size_t)b * 256 + wj * 4;
  const int tid = threadIdx.x;
  const int l = tid & 63, wv = tid >> 6;
  const int h = l >> 5, l31 = l & 31;
  const float escale = __expf(fminf(ls[head], LOGIT_MAX_F));
  const float M = escale + 16.f;
  {  // stage T (f32, 8 KB)
    const float* tp = tbuf + (size_t)blockIdx.x * 2048 + tid * 8;
    *(f4*)(&t_s[tid * 8]) = *(const f4*)(tp);
    *(f4*)(&t_s[tid * 8 + 4]) = *(const f4*)(tp + 4);
  }
  // anchor A-frags (K side): 2 chunks of 32 anchors, normalized
  bf16x8 akh[2][2], akl[2][2];
#pragma unroll
  for (int c = 0; c < 2; c++) {
    const int a = c * 32 + l31;
    const float* ap = anch + (abase + (a >> 2) * 16 + (a & 3)) * 128 + head * 32;
    f4 a0 = *(const f4*)(ap + h * 8);
    f4 a1 = *(const f4*)(ap + h * 8 + 4);
    f4 b0 = *(const f4*)(ap + 16 + h * 8);
    f4 b1 = *(const f4*)(ap + 16 + h * 8 + 4);
    float ss = 0.f;
#pragma unroll
    for (int e = 0; e < 4; e++)
      ss += a0[e] * a0[e] + a1[e] * a1[e] + b0[e] * b0[e] + b1[e] * b1[e];
    ss += __shfl_xor(ss, 32);
    const float ai = 1.f / fmaxf(sqrtf(ss), 1e-12f);
    pack_hilo8(a0[0] * ai, a0[1] * ai, a0[2] * ai, a0[3] * ai,
               a1[0] * ai, a1[1] * ai, a1[2] * ai, a1[3] * ai, akh[c][0], akl[c][0]);
    pack_hilo8(b0[0] * ai, b0[1] * ai, b0[2] * ai, b0[3] * ai,
               b1[0] * ai, b1[1] * ai, b1[2] * ai, b1[3] * ai, akh[c][1], akl[c][1]);
  }
  __syncthreads();
  // T B-frags: 4 k-steps of 16 anchors; lane needs T[a = s*16 + h*8 + e][d = l31]
  bf16x8 tfh[4], tfl[4];
#pragma unroll
  for (int s = 0; s < 4; s++) {
    float v8[8];
#pragma unroll
    for (int e = 0; e < 8; e++) v8[e] = t_s[(s * 16 + h * 8 + e) * 32 + l31];
    pack_hilo8(v8[0], v8[1], v8[2], v8[3], v8[4], v8[5], v8[6], v8[7], tfh[s], tfl[s]);
  }

#pragma unroll 1
  for (int qg = 0; qg < 8; qg++) {
    const int q = wv * 256 + qg * 32 + l31;
    const float* qp = qkvs + (rowbase + (q >> 4) * 64 + (q & 15)) * 384 + head * 32;
    f4 qa0 = *(const f4*)(qp + h * 8);
    f4 qa1 = *(const f4*)(qp + h * 8 + 4);
    f4 qb0 = *(const f4*)(qp + 16 + h * 8);
    f4 qb1 = *(const f4*)(qp + 16 + h * 8 + 4);
    float ss = 0.f;
#pragma unroll
    for (int e = 0; e < 4; e++)
      ss += qa0[e] * qa0[e] + qa1[e] * qa1[e] + qb0[e] * qb0[e] + qb1[e] * qb1[e];
    ss += __shfl_xor(ss, 32);
    const float qsc = escale / fmaxf(sqrtf(ss), 1e-12f);
    bf16x8 qbh[2], qbl[2];
    pack_hilo8(qa0[0] * qsc, qa0[1] * qsc, qa0[2] * qsc, qa0[3] * qsc,
               qa1[0] * qsc, qa1[1] * qsc, qa1[2] * qsc, qa1[3] * qsc, qbh[0], qbl[0]);
    pack_hilo8(qb0[0] * qsc, qb0[1] * qsc, qb0[2] * qsc, qb0[3] * qsc,
               qb1[0] * qsc, qb1[1] * qsc, qb1[2] * qsc, qb1[3] * qsc, qbh[1], qbl[1]);

    f32x16 st0 = {}, st1 = {};
    st0 = __builtin_amdgcn_mfma_f32_32x32x16_bf16(akh[0][0], qbh[0], st0, 0, 0, 0);
    st0 = __builtin_amdgcn_mfma_f32_32x32x16_bf16(akh[0][1], qbh[1], st0, 0, 0, 0);
    st0 = __builtin_amdgcn_mfma_f32_32x32x16_bf16(akh[0][0], qbl[0], st0, 0, 0, 0);
    st0 = __builtin_amdgcn_mfma_f32_32x32x16_bf16(akh[0][1], qbl[1], st0, 0, 0, 0);
    st0 = __builtin_amdgcn_mfma_f32_32x32x16_bf16(akl[0][0], qbh[0], st0, 0, 0, 0);
    st0 = __builtin_amdgcn_mfma_f32_32x32x16_bf16(akl[0][1], qbh[1], st0, 0, 0, 0);
    st1 = __builtin_amdgcn_mfma_f32_32x32x16_bf16(akh[1][0], qbh[0], st1, 0, 0, 0);
    st1 = __builtin_amdgcn_mfma_f32_32x32x16_bf16(akh[1][1], qbh[1], st1, 0, 0, 0);
    st1 = __builtin_amdgcn_mfma_f32_32x32x16_bf16(akh[1][0], qbl[0], st1, 0, 0, 0);
    st1 = __builtin_amdgcn_mfma_f32_32x32x16_bf16(akh[1][1], qbl[1], st1, 0, 0, 0);
    st1 = __builtin_amdgcn_mfma_f32_32x32x16_bf16(akl[1][0], qbh[0], st1, 0, 0, 0);
    st1 = __builtin_amdgcn_mfma_f32_32x32x16_bf16(akl[1][1], qbh[1], st1, 0, 0, 0);

    float p0[16], p1[16];
    float rs = 0.f;
    {
      const float* bp = bias2x + ((size_t)(head * 1024 + q)) * 64 + h * 4;
      f4 b0 = *(const f4*)(bp);
      f4 b1 = *(const f4*)(bp + 8);
      f4 b2 = *(const f4*)(bp + 16);
      f4 b3 = *(const f4*)(bp + 24);
#pragma unroll
      for (int r = 0; r < 16; r++) {
        const float bb = (r < 4) ? b0[r & 3] : (r < 8) ? b1[r & 3] : (r < 12) ? b2[r & 3] : b3[r & 3];
        const float pv = __expf(st0[r] + bb - M);
        p0[r] = pv;
        rs += pv;
      }
      f4 c0 = *(const f4*)(bp + 32);
      f4 c1 = *(const f4*)(bp + 40);
      f4 c2 = *(const f4*)(bp + 48);
      f4 c3 = *(const f4*)(bp + 56);
#pragma unroll
      for (int r = 0; r < 16; r++) {
        const float bb = (r < 4) ? c0[r & 3] : (r < 8) ? c1[r & 3] : (r < 12) ? c2[r & 3] : c3[r & 3];
        const float pv = __expf(st1[r] + bb - M);
        p1[r] = pv;
        rs += pv;
      }
    }
    rs += __shfl_xor(rs, 32);
    const float inv = 1.f / rs;

    f32x16 o = {};
#pragma unroll
    for (int s = 0; s < 4; s++) {
      bf16x8 pah, pal;
      if (s == 0)      pack_pa(p0[0], p0[1], p0[2], p0[3], p0[4], p0[5], p0[6], p0[7], pah, pal);
      else if (s == 1) pack_pa(p0[8], p0[9], p0[10], p0[11], p0[12], p0[13], p0[14], p0[15], pah, pal);
      else if (s == 2) pack_pa(p1[0], p1[1], p1[2], p1[3], p1[4], p1[5], p1[6], p1[7], pah, pal);
      else             pack_pa(p1[8], p1[9], p1[10], p1[11], p1[12], p1[13], p1[14], p1[15], pah, pal);
      o = __builtin_amdgcn_mfma_f32_32x32x16_bf16(pah, tfh[s], o, 0, 0, 0);
      o = __builtin_amdgcn_mfma_f32_32x32x16_bf16(pah, tfl[s], o, 0, 0, 0);
      o = __builtin_amdgcn_mfma_f32_32x32x16_bf16(pal, tfh[s], o, 0, 0, 0);
    }
#pragma unroll
    for (int r = 0; r < 16; r++) {
      const int qr = (r & 3) + 8 * (r >> 2) + 4 * h;
      const float iv = __shfl(inv, qr);
      const int qo = wv * 256 + qg * 32 + qr;
      outp[(rowbase + (qo >> 4) * 64 + (qo & 15)) * 256 + 128 + head * 32 + l31] = o[r] * iv;
    }
  }
}

// ---------------------------------------------------------------- launch
extern "C" void kernel_launch(void* const* d_in, const int* in_sizes, int n_in,
                              void* d_out, int out_size, void* d_ws, size_t ws_size,
                              hipStream_t stream) {
  (void)in_sizes; (void)n_in; (void)out_size;
  const float* x        = (const float*)d_in[0];
  const float* w_qkv    = (const float*)d_in[1];
  const float* b_qkv    = (const float*)d_in[2];
  const float* w_anchor = (const float*)d_in[3];
  const float* b_anchor = (const float*)d_in[4];
  const float* ls_w     = (const float*)d_in[5];
  const float* cw1_w    = (const float*)d_in[6];
  const float* cb1_w    = (const float*)d_in[7];
  const float* cw2_w    = (const float*)d_in[8];
  const float* ls_s1    = (const float*)d_in[9];
  const float* cw1_s1   = (const float*)d_in[10];
  const float* cb1_s1   = (const float*)d_in[11];
  const float* cw2_s1   = (const float*)d_in[12];
  const float* ls_s2    = (const float*)d_in[13];
  const float* cw1_s2   = (const float*)d_in[14];
  const float* cb1_s2   = (const float*)d_in[15];
  const float* cw2_s2   = (const float*)d_in[16];
  const float* w_proj   = (const float*)d_in[17];
  const float* b_proj   = (const float*)d_in[18];
  float* out = (float*)d_out;

  // ---- adaptive chunking over batch
  const size_t fixed_bytes =
      (size_t)4096 * 256 * 4 +              // pooled
      (size_t)4096 * 128 * 4 +              // anch
      (size_t)961 * 16 + (size_t)1501 * 16 * 2 +
      (size_t)(768 + 256) * 256 * 2 * 2 +   // transposed bf16 weights hi+lo
      (size_t)4 * 256 * 256 * 4 +           // expanded window bias
      (size_t)4 * 64 * 1024 * 4 +           // expanded stripe1 bias
      (size_t)4 * 1024 * 64 * 4 +           // expanded stripe2 bias
      64 * 256;                             // slack
  const size_t per_nb = (size_t)4096 * 384 * 4 + (size_t)16 * 2048 * 4 +
                        (size_t)4096 * 256 * 2 * 2;
  int NB = 16;
  while (NB > 1) {
    size_t need = fixed_bytes + (size_t)NB * per_nb;
    if (need <= ws_size) break;
    NB >>= 1;
  }
  const int nchunks = 16 / NB;

  char* ws = (char*)d_ws;
  size_t off = 0;
  auto take = [&](size_t bytes) {
    char* p = ws + off;
    off += (bytes + 255) & ~(size_t)255;
    return p;
  };
  float* pooled = (float*)take((size_t)4096 * 256 * 4);
  float* anch   = (float*)take((size_t)4096 * 128 * 4);
  float* sbt_w  = (float*)take((size_t)961 * 16);
  float* sbt_s1 = (float*)take((size_t)1501 * 16);
  float* sbt_s2 = (float*)take((size_t)1501 * 16);
  float* bias2w = (float*)take((size_t)4 * 256 * 256 * 4);
  float* bias1x = (float*)take((size_t)4 * 64 * 1024 * 4);
  float* bias2x = (float*)take((size_t)4 * 1024 * 64 * 4);
  unsigned short* wqh = (unsigned short*)take((size_t)768 * 256 * 2);
  unsigned short* wql = (unsigned short*)take((size_t)768 * 256 * 2);
  unsigned short* wph = (unsigned short*)take((size_t)256 * 256 * 2);
  unsigned short* wpl = (unsigned short*)take((size_t)256 * 256 * 2);
  float* tbuf   = (float*)take((size_t)NB * 16 * 2048 * 4);
  unsigned short* xhi = (unsigned short*)take((size_t)NB * 4096 * 256 * 2);
  unsigned short* xlo = (unsigned short*)take((size_t)NB * 4096 * 256 * 2);
  float* qkvh   = (float*)take((size_t)NB * 4096 * 384 * 4);

  // ---- one-time prep
  k_cpb<<<961, 64, 0, stream>>>(cw1_w, cb1_w, cw2_w, sbt_w, 31, 1.f / 15.f, 1.f / 15.f, -15, -15);
  k_cpb<<<1501, 64, 0, stream>>>(cw1_s1, cb1_s1, cw2_s1, sbt_s1, 19, 1.f / 39.f, 1.f / 9.f, -39, -9);
  k_cpb<<<1501, 64, 0, stream>>>(cw1_s2, cb1_s2, cw2_s2, sbt_s2, 19, 1.f / 39.f, 1.f / 9.f, -39, -9);
  k_bias_expand<<<1024, 256, 0, stream>>>(sbt_w, bias2w);
  k_bias1x<<<256, 256, 0, stream>>>(sbt_s1, bias1x);
  k_bias2x<<<4096, 64, 0, stream>>>(sbt_s2, bias2x);
  k_cvt_wt<<<768, 256, 0, stream>>>(w_qkv, wqh, wql, 768);
  k_cvt_wt<<<256, 256, 0, stream>>>(w_proj, wph, wpl, 256);
  k_pool<<<4096, 256, 0, stream>>>(x, pooled);
  k_gemm<<<(4096 / 64) * 2, 256, 0, stream>>>(pooled, w_anchor, b_anchor, anch, 4096, 128, 256, 128);

  // ---- chunked over batch
  const int M = NB * 4096;
  for (int c = 0; c < nchunks; c++) {
    const float* xc = x + (size_t)c * NB * 4096 * 256;
    float* outc = out + (size_t)c * NB * 4096 * 256;
    const float* anchc = anch + (size_t)c * NB * 256 * 128;
    k_cvt<<<NB * 512, 256, 0, stream>>>(xc, xhi, xlo);
    // window half (qkv channels 0..383)
    k_gemm_bf16pair<<<(M / 128) * 3, 256, 0, stream>>>(xhi, xlo, wqh, wql, b_qkv, qkvh, M, 384);
    k_win_attn_mfma<<<NB * 64, 256, 0, stream>>>(qkvh, bias2w, ls_w, outc);
    // stripe half (qkv channels 384..767) overwrites qkvh
    k_gemm_bf16pair<<<(M / 128) * 3, 256, 0, stream>>>(xhi, xlo, wqh + 384 * 256, wql + 384 * 256,
                                                       b_qkv + 384, qkvh, M, 384);
    k_stripe1_mfma<<<NB * 16, 256, 0, stream>>>(qkvh, anchc, bias1x, ls_s1, tbuf);
    k_stripe2_mfma<<<NB * 16, 256, 0, stream>>>(qkvh, anchc, tbuf, bias2x, ls_s2, outc);
  }
  // ---- final projection (reads bf16 copy of out, writes out -> no aliasing hazard)
  for (int c = 0; c < nchunks; c++) {
    float* outc = out + (size_t)c * NB * 4096 * 256;
    k_cvt<<<NB * 512, 256, 0, stream>>>(outc, xhi, xlo);
    k_gemm_bf16pair<<<(M / 128) * 2, 256, 0, stream>>>(xhi, xlo, wph, wpl, b_proj, outc, M, 256);
  }
}

// Round 7
// 491.601 us; speedup vs baseline: 2.5774x; 1.0528x over previous
//
#include <hip/hip_runtime.h>
#include <math.h>

typedef float f4 __attribute__((ext_vector_type(4)));
typedef float f32x4 __attribute__((ext_vector_type(4)));
typedef float f32x16 __attribute__((ext_vector_type(16)));
typedef __bf16 bf16;
typedef bf16 bf16x8 __attribute__((ext_vector_type(8)));
typedef unsigned short us8 __attribute__((ext_vector_type(8)));

#define LOGIT_MAX_F 4.605170185988092f

// ---------------------------------------------------------------- bf16 helpers
__device__ __forceinline__ unsigned short bf_rne(float x) {
  unsigned u = __float_as_uint(x);
  u += 0x7fff + ((u >> 16) & 1);
  return (unsigned short)(u >> 16);
}
__device__ __forceinline__ float bf_to_f(unsigned short h) {
  return __uint_as_float((unsigned)h << 16);
}
__device__ __forceinline__ void stage16(const unsigned short* g, unsigned short* l) {
  __builtin_amdgcn_global_load_lds(
      (const __attribute__((address_space(1))) unsigned int*)g,
      (__attribute__((address_space(3))) unsigned int*)l, 16, 0, 0);
}
// packed f32x2 -> bf16x2 (RNE), no builtin on gfx950 -> inline asm
__device__ __forceinline__ unsigned cvt_pk_bf16(float a, float b) {
  unsigned r;
  asm("v_cvt_pk_bf16_f32 %0, %1, %2" : "=v"(r) : "v"(a), "v"(b));
  return r;
}
// lane i <-> lane i+32 half-exchange; s_nops guard VALU<->permlane hazards
__device__ __forceinline__ void pl32swap(unsigned& a, unsigned& b) {
  asm volatile("s_nop 1\n\tv_permlane32_swap_b32 %0, %1\n\ts_nop 1"
               : "+v"(a), "+v"(b));
}
union FRU { unsigned u[4]; bf16x8 v8; };

// build hi/lo bf16x8 frags from 8 f32 (memory order = frag elem order)
__device__ __forceinline__ void pack_hilo8(float v0, float v1, float v2, float v3,
                                           float v4, float v5, float v6, float v7,
                                           bf16x8& hi, bf16x8& lo) {
  unsigned X0 = cvt_pk_bf16(v0, v1), X1 = cvt_pk_bf16(v2, v3);
  unsigned X2 = cvt_pk_bf16(v4, v5), X3 = cvt_pk_bf16(v6, v7);
  unsigned Y0 = cvt_pk_bf16(v0 - __uint_as_float(X0 << 16), v1 - __uint_as_float(X0 & 0xffff0000u));
  unsigned Y1 = cvt_pk_bf16(v2 - __uint_as_float(X1 << 16), v3 - __uint_as_float(X1 & 0xffff0000u));
  unsigned Y2 = cvt_pk_bf16(v4 - __uint_as_float(X2 << 16), v5 - __uint_as_float(X2 & 0xffff0000u));
  unsigned Y3 = cvt_pk_bf16(v6 - __uint_as_float(X3 << 16), v7 - __uint_as_float(X3 & 0xffff0000u));
  FRU a, c;
  a.u[0] = X0; a.u[1] = X1; a.u[2] = X2; a.u[3] = X3;
  c.u[0] = Y0; c.u[1] = Y1; c.u[2] = Y2; c.u[3] = Y3;
  hi = a.v8; lo = c.v8;
}
// P regs (S^T layout, one 16-key step) -> PV A-frag (hi/lo) incl. cross-half swap
__device__ __forceinline__ void pack_pa(float p0, float p1, float p2, float p3,
                                        float p4, float p5, float p6, float p7,
                                        bf16x8& hi, bf16x8& lo) {
  unsigned X0 = cvt_pk_bf16(p0, p1), X1 = cvt_pk_bf16(p2, p3);
  unsigned X2 = cvt_pk_bf16(p4, p5), X3 = cvt_pk_bf16(p6, p7);
  unsigned Y0 = cvt_pk_bf16(p0 - __uint_as_float(X0 << 16), p1 - __uint_as_float(X0 & 0xffff0000u));
  unsigned Y1 = cvt_pk_bf16(p2 - __uint_as_float(X1 << 16), p3 - __uint_as_float(X1 & 0xffff0000u));
  unsigned Y2 = cvt_pk_bf16(p4 - __uint_as_float(X2 << 16), p5 - __uint_as_float(X2 & 0xffff0000u));
  unsigned Y3 = cvt_pk_bf16(p6 - __uint_as_float(X3 << 16), p7 - __uint_as_float(X3 & 0xffff0000u));
  pl32swap(X0, X2); pl32swap(X1, X3);
  pl32swap(Y0, Y2); pl32swap(Y1, Y3);
  FRU a, c;
  a.u[0] = X0; a.u[1] = X1; a.u[2] = X2; a.u[3] = X3;
  c.u[0] = Y0; c.u[1] = Y1; c.u[2] = Y2; c.u[3] = Y3;
  hi = a.v8; lo = c.v8;
}

// ---------------------------------------------------------------- CPB tables
__global__ __launch_bounds__(64) void k_cpb(const float* __restrict__ w1,
                                            const float* __restrict__ b1,
                                            const float* __restrict__ w2,
                                            float* __restrict__ sbt,
                                            int n_cw, float inv_p0, float inv_p1,
                                            int ts_n0, int ts_n1) {
  int row = blockIdx.x;
  int lane = threadIdx.x;
  int ih = row / n_cw, iw = row % n_cw;
  float v0 = (float)(ts_n0 + ih) * inv_p0 * 8.0f;
  float v1 = (float)(ts_n1 + iw) * inv_p1 * 8.0f;
  v0 = (v0 >= 0.f ? 1.f : -1.f) * log2f(fabsf(v0) + 1.f) * (1.f / 3.f);
  v1 = (v1 >= 0.f ? 1.f : -1.f) * log2f(fabsf(v1) + 1.f) * (1.f / 3.f);
  float a0 = 0.f, a1 = 0.f, a2 = 0.f, a3 = 0.f;
  for (int j = lane; j < 512; j += 64) {
    float h = v0 * w1[j] + v1 * w1[512 + j] + b1[j];
    h = fmaxf(h, 0.f);
    a0 += h * w2[j * 4 + 0];
    a1 += h * w2[j * 4 + 1];
    a2 += h * w2[j * 4 + 2];
    a3 += h * w2[j * 4 + 3];
  }
#pragma unroll
  for (int off = 32; off > 0; off >>= 1) {
    a0 += __shfl_down(a0, off);
    a1 += __shfl_down(a1, off);
    a2 += __shfl_down(a2, off);
    a3 += __shfl_down(a3, off);
  }
  if (lane == 0) {
    sbt[row * 4 + 0] = 16.f / (1.f + expf(-a0));
    sbt[row * 4 + 1] = 16.f / (1.f + expf(-a1));
    sbt[row * 4 + 2] = 16.f / (1.f + expf(-a2));
    sbt[row * 4 + 3] = 16.f / (1.f + expf(-a3));
  }
}

// ---------------------------------------------------------------- expand window bias to [head][q][key]
__global__ __launch_bounds__(256) void k_bias_expand(const float* __restrict__ sbt,
                                                     float* __restrict__ bias2) {
  const int q = blockIdx.x & 255, head = blockIdx.x >> 8;
  const int key = threadIdx.x;
  const int idx = ((q >> 4) - (key >> 4) + 15) * 31 + ((q & 15) - (key & 15) + 15);
  bias2[((size_t)(head * 256 + q)) * 256 + key] = sbt[idx * 4 + head];
}

// ---------------------------------------------------------------- expand stripe biases
// bias1x[head][a(64)][key(1024)]  (anchor->window, stage 1)
__global__ __launch_bounds__(256) void k_bias1x(const float* __restrict__ sbt,
                                                float* __restrict__ bx) {
  const int head = blockIdx.x >> 6, a = blockIdx.x & 63;
#pragma unroll
  for (int k4 = 0; k4 < 4; k4++) {
    const int key = threadIdx.x + k4 * 256;
    const int idx = ((a >> 2) - (key >> 4) + 63) * 19 + (a & 3) - (key & 15) + 15;
    bx[((size_t)(head * 64 + a)) * 1024 + key] = sbt[idx * 4 + head];
  }
}
// bias2x[head][q(1024)][a(64)]  (window->anchor, stage 2)
__global__ __launch_bounds__(64) void k_bias2x(const float* __restrict__ sbt,
                                               float* __restrict__ bx) {
  const int head = blockIdx.x >> 10, q = blockIdx.x & 1023;
  const int a = threadIdx.x;
  const int idx = ((q >> 4) - (a >> 2) + 15) * 19 + (q & 15) - (a & 3) + 3;
  bx[((size_t)(head * 1024 + q)) * 64 + a] = sbt[idx * 4 + head];
}

// ---------------------------------------------------------------- 4x4 mean pool
__global__ __launch_bounds__(256) void k_pool(const float* __restrict__ x,
                                              float* __restrict__ pooled) {
  int blk = blockIdx.x;            // (b, gi, gj)
  int c = threadIdx.x;
  int b = blk >> 8, gi = (blk >> 4) & 15, gj = blk & 15;
  const float* xp = x + (size_t)b * 4096 * 256 + c;
  float s = 0.f;
#pragma unroll
  for (int di = 0; di < 4; di++)
#pragma unroll
    for (int dj = 0; dj < 4; dj++)
      s += xp[(size_t)((gi * 4 + di) * 64 + gj * 4 + dj) * 256];
  pooled[(size_t)blk * 256 + c] = s * 0.0625f;
}

// ---------------------------------------------------------------- f32 GEMM 64-tile (small, anchor only)
__global__ __launch_bounds__(256) void k_gemm(const float* __restrict__ A,
                                              const float* __restrict__ W,
                                              const float* __restrict__ bias,
                                              float* __restrict__ C,
                                              int M, int N, int K, int ldw) {
  __shared__ float a_s[16][64];
  __shared__ float w_s[16][64];
  const int ntg = N >> 6;
  const int mb = blockIdx.x / ntg, nb = blockIdx.x % ntg;
  const int m0 = mb << 6, n0 = nb << 6;
  const int tid = threadIdx.x;
  const int tx = tid & 15, ty = tid >> 4;
  const int ar = tid >> 2, ac4 = (tid & 3) << 2;
  const int wk = tid >> 4, wc4 = (tid & 15) << 2;
  float acc[4][4] = {};
  for (int k0 = 0; k0 < K; k0 += 16) {
    f4 av = *(const f4*)(A + (size_t)(m0 + ar) * K + k0 + ac4);
    f4 wv = *(const f4*)(W + (size_t)(k0 + wk) * ldw + n0 + wc4);
    __syncthreads();
    a_s[ac4 + 0][ar] = av[0];
    a_s[ac4 + 1][ar] = av[1];
    a_s[ac4 + 2][ar] = av[2];
    a_s[ac4 + 3][ar] = av[3];
    *(f4*)(&w_s[wk][wc4]) = wv;
    __syncthreads();
#pragma unroll
    for (int kk = 0; kk < 16; kk++) {
      f4 a4 = *(const f4*)(&a_s[kk][ty << 2]);
      f4 w4 = *(const f4*)(&w_s[kk][tx << 2]);
#pragma unroll
      for (int i = 0; i < 4; i++)
#pragma unroll
        for (int j = 0; j < 4; j++)
          acc[i][j] = fmaf(a4[i], w4[j], acc[i][j]);
    }
  }
#pragma unroll
  for (int i = 0; i < 4; i++) {
    const int row = m0 + (ty << 2) + i;
#pragma unroll
    for (int j = 0; j < 4; j++) {
      const int col = n0 + (tx << 2) + j;
      C[(size_t)row * N + col] = acc[i][j] + bias[col];
    }
  }
}

// ---------------------------------------------------------------- f32 -> bf16 hi/lo pair
__global__ __launch_bounds__(256) void k_cvt(const float* __restrict__ in,
                                             unsigned short* __restrict__ hi,
                                             unsigned short* __restrict__ lo) {
  const size_t i = ((size_t)blockIdx.x * 256 + threadIdx.x) * 8;
  f4 v0 = *(const f4*)(in + i);
  f4 v1 = *(const f4*)(in + i + 4);
  us8 h, l;
#pragma unroll
  for (int e = 0; e < 8; e++) {
    float xv = e < 4 ? v0[e] : v1[e - 4];
    unsigned short hh = bf_rne(xv);
    h[e] = hh;
    l[e] = bf_rne(xv - bf_to_f(hh));
  }
  *(us8*)(hi + i) = h;
  *(us8*)(lo + i) = l;
}

// ---------------------------------------------------------------- weight convert + transpose
__global__ __launch_bounds__(256) void k_cvt_wt(const float* __restrict__ W,
                                                unsigned short* __restrict__ hi,
                                                unsigned short* __restrict__ lo,
                                                int N) {
  const int n = blockIdx.x, k = threadIdx.x;
  float xv = W[(size_t)k * N + n];
  unsigned short hh = bf_rne(xv);
  hi[n * 256 + k] = hh;
  lo[n * 256 + k] = bf_rne(xv - bf_to_f(hh));
}

// ---------------------------------------------------------------- split-bf16 MFMA GEMM
// XCD-aware block swizzle (T1): bijection on blockIdx so each XCD's L2 sees a
// contiguous tile range. Guarded by nwg%8==0 (always true for our grids).
__global__ __launch_bounds__(256) void k_gemm_bf16pair(
    const unsigned short* __restrict__ Ahi, const unsigned short* __restrict__ Alo,
    const unsigned short* __restrict__ Bthi, const unsigned short* __restrict__ Btlo,
    const float* __restrict__ bias, float* __restrict__ C, int M, int N) {
  __shared__ __align__(16) unsigned short ah_s[128 * 32];
  __shared__ __align__(16) unsigned short al_s[128 * 32];
  __shared__ __align__(16) unsigned short bh_s[128 * 32];
  __shared__ __align__(16) unsigned short bl_s[128 * 32];
  const int ntg = N >> 7;
  int bid = blockIdx.x;
  {
    const int nwg = gridDim.x;
    if ((nwg & 7) == 0) {
      const int cpx = nwg >> 3;
      bid = (bid & 7) * cpx + (bid >> 3);
    }
  }
  const int m0 = (bid / ntg) << 7, n0 = (bid % ntg) << 7;
  const int tid = threadIdx.x;
  const int w = tid >> 6, l = tid & 63;
  const int wr = w >> 1, wc = w & 1;
  const int lr = l & 15, kg = l >> 4;
  const int srow = tid >> 2;
  const int scol = (tid & 3) << 3;
  const int lds_w = w * 512;
  f32x4 acc[4][4] = {};

  for (int k0 = 0; k0 < 256; k0 += 32) {
    const size_t ga0 = (size_t)(m0 + srow) * 256 + k0 + scol;
    const size_t ga1 = (size_t)(m0 + 64 + srow) * 256 + k0 + scol;
    const size_t gb0 = (size_t)(n0 + srow) * 256 + k0 + scol;
    const size_t gb1 = (size_t)(n0 + 64 + srow) * 256 + k0 + scol;
    stage16(Ahi + ga0, ah_s + lds_w);
    stage16(Ahi + ga1, ah_s + 2048 + lds_w);
    stage16(Alo + ga0, al_s + lds_w);
    stage16(Alo + ga1, al_s + 2048 + lds_w);
    stage16(Bthi + gb0, bh_s + lds_w);
    stage16(Bthi + gb1, bh_s + 2048 + lds_w);
    stage16(Btlo + gb0, bl_s + lds_w);
    stage16(Btlo + gb1, bl_s + 2048 + lds_w);
    __syncthreads();
    bf16x8 a_h[4], a_l[4], b_h[4], b_l[4];
#pragma unroll
    for (int i = 0; i < 4; i++) {
      const int r = wr * 64 + i * 16 + lr;
      a_h[i] = *(const bf16x8*)(ah_s + r * 32 + kg * 8);
      a_l[i] = *(const bf16x8*)(al_s + r * 32 + kg * 8);
    }
#pragma unroll
    for (int j = 0; j < 4; j++) {
      const int r = wc * 64 + j * 16 + lr;
      b_h[j] = *(const bf16x8*)(bh_s + r * 32 + kg * 8);
      b_l[j] = *(const bf16x8*)(bl_s + r * 32 + kg * 8);
    }
#pragma unroll
    for (int i = 0; i < 4; i++)
#pragma unroll
      for (int j = 0; j < 4; j++) {
        acc[i][j] = __builtin_amdgcn_mfma_f32_16x16x32_bf16(a_h[i], b_h[j], acc[i][j], 0, 0, 0);
        acc[i][j] = __builtin_amdgcn_mfma_f32_16x16x32_bf16(a_h[i], b_l[j], acc[i][j], 0, 0, 0);
        acc[i][j] = __builtin_amdgcn_mfma_f32_16x16x32_bf16(a_l[i], b_h[j], acc[i][j], 0, 0, 0);
      }
    __syncthreads();
  }
#pragma unroll
  for (int j = 0; j < 4; j++) {
    const int col = n0 + wc * 64 + j * 16 + lr;
    const float bj = bias[col];
#pragma unroll
    for (int i = 0; i < 4; i++) {
      const int row0 = m0 + wr * 64 + i * 16 + kg * 4;
#pragma unroll
      for (int r = 0; r < 4; r++)
        C[(size_t)(row0 + r) * N + col] = acc[i][j][r] + bj;
    }
  }
}

// ---------------------------------------------------------------- window attention (MFMA, split-bf16)
// block = (window, head): 256 tokens x 256 keys x d=32. 4 waves, wave w owns q rows 64w..64w+63.
// Swapped QK^T (A=K rows=key, B=Q cols=q) => scores lane-local per q; fixed softmax max M=escale+16.
// K staged normalized hi/lo [256][40 pad]; V^T staged hi/lo [32][264 pad]. ~73 KB LDS, 2 blk/CU.
__global__ __launch_bounds__(256) void k_win_attn_mfma(
    const float* __restrict__ qkvw, const float* __restrict__ bias2,
    const float* __restrict__ ls, float* __restrict__ outp) {
  __shared__ __align__(16) unsigned short kh_s[256 * 40];
  __shared__ __align__(16) unsigned short kl_s[256 * 40];
  __shared__ __align__(16) unsigned short vth_s[32 * 264];
  __shared__ __align__(16) unsigned short vtl_s[32 * 264];
  const int head = blockIdx.x & 3, win = blockIdx.x >> 2;
  const int b = win >> 4, wh = (win >> 2) & 3, ww = win & 3;
  const size_t rowbase = (size_t)b * 4096 + wh * 1024 + ww * 16;
  const int tid = threadIdx.x;
  const int l = tid & 63, wv = tid >> 6;
  const int h = l >> 5, l31 = l & 31;
  const float escale = __expf(fminf(ls[head], LOGIT_MAX_F));
  const float M = escale + 16.f;

  {
    const int key = tid;
    const float* kp = qkvw + (rowbase + (key >> 4) * 64 + (key & 15)) * 384 + 128 + head * 32;
    f4 kv[8];
    float ss = 0.f;
#pragma unroll
    for (int c = 0; c < 8; c++) {
      kv[c] = *(const f4*)(kp + c * 4);
      ss += kv[c][0] * kv[c][0] + kv[c][1] * kv[c][1] + kv[c][2] * kv[c][2] + kv[c][3] * kv[c][3];
    }
    const float kinv = 1.f / fmaxf(sqrtf(ss), 1e-12f);
#pragma unroll
    for (int g = 0; g < 4; g++) {
      us8 h8, l8;
#pragma unroll
      for (int e = 0; e < 8; e++) {
        const float v = ((e < 4) ? kv[g * 2][e] : kv[g * 2 + 1][e - 4]) * kinv;
        const unsigned short hh = bf_rne(v);
        h8[e] = hh;
        l8[e] = bf_rne(v - bf_to_f(hh));
      }
      *(us8*)(kh_s + key * 40 + g * 8) = h8;
      *(us8*)(kl_s + key * 40 + g * 8) = l8;
    }
    const float* vp = kp + 128;  // V channels
#pragma unroll
    for (int c = 0; c < 8; c++) {
      f4 vvv = *(const f4*)(vp + c * 4);
#pragma unroll
      for (int e = 0; e < 4; e++) {
        const int d = c * 4 + e;
        const unsigned short hh = bf_rne(vvv[e]);
        vth_s[d * 264 + key] = hh;
        vtl_s[d * 264 + key] = bf_rne(vvv[e] - bf_to_f(hh));
      }
    }
  }

  bf16x8 qfh[2][2], qfl[2][2];
  int qtok[2];
#pragma unroll
  for (int qt = 0; qt < 2; qt++) {
    qtok[qt] = wv * 64 + qt * 32 + l31;
    const float* qp = qkvw + (rowbase + (qtok[qt] >> 4) * 64 + (qtok[qt] & 15)) * 384 + head * 32;
    f4 qa0 = *(const f4*)(qp + h * 8);
    f4 qa1 = *(const f4*)(qp + h * 8 + 4);
    f4 qb0 = *(const f4*)(qp + 16 + h * 8);
    f4 qb1 = *(const f4*)(qp + 16 + h * 8 + 4);
    float ssq = 0.f;
#pragma unroll
    for (int e = 0; e < 4; e++)
      ssq += qa0[e] * qa0[e] + qa1[e] * qa1[e] + qb0[e] * qb0[e] + qb1[e] * qb1[e];
    ssq += __shfl_xor(ssq, 32);
    const float qsc = escale / fmaxf(sqrtf(ssq), 1e-12f);
    pack_hilo8(qa0[0] * qsc, qa0[1] * qsc, qa0[2] * qsc, qa0[3] * qsc,
               qa1[0] * qsc, qa1[1] * qsc, qa1[2] * qsc, qa1[3] * qsc,
               qfh[qt][0], qfl[qt][0]);
    pack_hilo8(qb0[0] * qsc, qb0[1] * qsc, qb0[2] * qsc, qb0[3] * qsc,
               qb1[0] * qsc, qb1[1] * qsc, qb1[2] * qsc, qb1[3] * qsc,
               qfh[qt][1], qfl[qt][1]);
  }
  __syncthreads();

  f32x16 o0 = {}, o1 = {};
  float rs0 = 0.f, rs1 = 0.f;
#pragma unroll 1
  for (int kt = 0; kt < 8; kt++) {
    const int kbase = (kt * 32 + l31) * 40 + h * 8;
    const bf16x8 kh0 = *(const bf16x8*)(kh_s + kbase);
    const bf16x8 kh1 = *(const bf16x8*)(kh_s + kbase + 16);
    const bf16x8 kl0 = *(const bf16x8*)(kl_s + kbase);
    const bf16x8 kl1 = *(const bf16x8*)(kl_s + kbase + 16);
    f32x16 st0 = {}, st1 = {};
    st0 = __builtin_amdgcn_mfma_f32_32x32x16_bf16(kh0, qfh[0][0], st0, 0, 0, 0);
    st0 = __builtin_amdgcn_mfma_f32_32x32x16_bf16(kh1, qfh[0][1], st0, 0, 0, 0);
    st0 = __builtin_amdgcn_mfma_f32_32x32x16_bf16(kh0, qfl[0][0], st0, 0, 0, 0);
    st0 = __builtin_amdgcn_mfma_f32_32x32x16_bf16(kh1, qfl[0][1], st0, 0, 0, 0);
    st0 = __builtin_amdgcn_mfma_f32_32x32x16_bf16(kl0, qfh[0][0], st0, 0, 0, 0);
    st0 = __builtin_amdgcn_mfma_f32_32x32x16_bf16(kl1, qfh[0][1], st0, 0, 0, 0);
    st1 = __builtin_amdgcn_mfma_f32_32x32x16_bf16(kh0, qfh[1][0], st1, 0, 0, 0);
    st1 = __builtin_amdgcn_mfma_f32_32x32x16_bf16(kh1, qfh[1][1], st1, 0, 0, 0);
    st1 = __builtin_amdgcn_mfma_f32_32x32x16_bf16(kh0, qfl[1][0], st1, 0, 0, 0);
    st1 = __builtin_amdgcn_mfma_f32_32x32x16_bf16(kh1, qfl[1][1], st1, 0, 0, 0);
    st1 = __builtin_amdgcn_mfma_f32_32x32x16_bf16(kl0, qfh[1][0], st1, 0, 0, 0);
    st1 = __builtin_amdgcn_mfma_f32_32x32x16_bf16(kl1, qfh[1][1], st1, 0, 0, 0);

    float p0[16], p1[16];
    {
      const float* bp = bias2 + ((size_t)(head * 256 + qtok[0])) * 256 + kt * 32 + h * 4;
      f4 b0 = *(const f4*)(bp);
      f4 b1 = *(const f4*)(bp + 8);
      f4 b2 = *(const f4*)(bp + 16);
      f4 b3 = *(const f4*)(bp + 24);
      float a = 0.f;
#pragma unroll
      for (int r = 0; r < 16; r++) {
        const float bb = (r < 4) ? b0[r & 3] : (r < 8) ? b1[r & 3] : (r < 12) ? b2[r & 3] : b3[r & 3];
        const float pv = __expf(st0[r] + bb - M);
        p0[r] = pv;
        a += pv;
      }
      rs0 += a;
    }
    {
      const float* bp = bias2 + ((size_t)(head * 256 + qtok[1])) * 256 + kt * 32 + h * 4;
      f4 b0 = *(const f4*)(bp);
      f4 b1 = *(const f4*)(bp + 8);
      f4 b2 = *(const f4*)(bp + 16);
      f4 b3 = *(const f4*)(bp + 24);
      float a = 0.f;
#pragma unroll
      for (int r = 0; r < 16; r++) {
        const float bb = (r < 4) ? b0[r & 3] : (r < 8) ? b1[r & 3] : (r < 12) ? b2[r & 3] : b3[r & 3];
        const float pv = __expf(st1[r] + bb - M);
        p1[r] = pv;
        a += pv;
      }
      rs1 += a;
    }

#pragma unroll
    for (int s = 0; s < 2; s++) {
      const int vbase = l31 * 264 + kt * 32 + s * 16 + h * 8;
      const bf16x8 vh = *(const bf16x8*)(vth_s + vbase);
      const bf16x8 vl = *(const bf16x8*)(vtl_s + vbase);
      bf16x8 pah, pal;
      if (s == 0)
        pack_pa(p0[0], p0[1], p0[2], p0[3], p0[4], p0[5], p0[6], p0[7], pah, pal);
      else
        pack_pa(p0[8], p0[9], p0[10], p0[11], p0[12], p0[13], p0[14], p0[15], pah, pal);
      o0 = __builtin_amdgcn_mfma_f32_32x32x16_bf16(pah, vh, o0, 0, 0, 0);
      o0 = __builtin_amdgcn_mfma_f32_32x32x16_bf16(pah, vl, o0, 0, 0, 0);
      o0 = __builtin_amdgcn_mfma_f32_32x32x16_bf16(pal, vh, o0, 0, 0, 0);
      if (s == 0)
        pack_pa(p1[0], p1[1], p1[2], p1[3], p1[4], p1[5], p1[6], p1[7], pah, pal);
      else
        pack_pa(p1[8], p1[9], p1[10], p1[11], p1[12], p1[13], p1[14], p1[15], pah, pal);
      o1 = __builtin_amdgcn_mfma_f32_32x32x16_bf16(pah, vh, o1, 0, 0, 0);
      o1 = __builtin_amdgcn_mfma_f32_32x32x16_bf16(pah, vl, o1, 0, 0, 0);
      o1 = __builtin_amdgcn_mfma_f32_32x32x16_bf16(pal, vh, o1, 0, 0, 0);
    }
  }

  const float inv0 = 1.f / fmaxf(rs0 + __shfl_xor(rs0, 32), 1e-37f);
  const float inv1 = 1.f / fmaxf(rs1 + __shfl_xor(rs1, 32), 1e-37f);
#pragma unroll
  for (int r = 0; r < 16; r++) {
    const int qrow = (r & 3) + 8 * (r >> 2) + 4 * h;
    const float iv0 = __shfl(inv0, qrow);
    const int qq0 = wv * 64 + qrow;
    outp[(rowbase + (qq0 >> 4) * 64 + (qq0 & 15)) * 256 + head * 32 + l31] = o0[r] * iv0;
    const float iv1 = __shfl(inv1, qrow);
    const int qq1 = wv * 64 + 32 + qrow;
    outp[(rowbase + (qq1 >> 4) * 64 + (qq1 & 15)) * 256 + head * 32 + l31] = o1[r] * iv1;
  }
}

// ---------------------------------------------------------------- stripe stage 1 (MFMA)
// block = (b, wj, head): 64 anchors (q) x 1024 keys. 4 waves, wave owns 256 keys.
// K/V loaded global->reg, split-bf16; fixed softmax max; cross-wave LDS reduce.
__global__ __launch_bounds__(256) void k_stripe1_mfma(
    const float* __restrict__ qkvs, const float* __restrict__ anch,
    const float* __restrict__ bias1x, const float* __restrict__ ls,
    float* __restrict__ tbuf) {
  __shared__ float opart[4][64][33];
  __shared__ float rsp[4][64];
  const int head = blockIdx.x & 3, sb = blockIdx.x >> 2;
  const int b = sb >> 2, wj = sb & 3;
  const size_t rowbase = (size_t)b * 4096 + wj * 16;
  const size_t abase = (size_t)b * 256 + wj * 4;
  const int tid = threadIdx.x;
  const int l = tid & 63, wv = tid >> 6;
  const int h = l >> 5, l31 = l & 31;
  const float escale = __expf(fminf(ls[head], LOGIT_MAX_F));
  const float M = escale + 16.f;

  // anchor Q frags (B operand), 2 groups of 32, scaled escale/||a||
  bf16x8 qfh[2][2], qfl[2][2];
#pragma unroll
  for (int g = 0; g < 2; g++) {
    const int a = g * 32 + l31;
    const float* ap = anch + (abase + (a >> 2) * 16 + (a & 3)) * 128 + head * 32;
    f4 qa0 = *(const f4*)(ap + h * 8);
    f4 qa1 = *(const f4*)(ap + h * 8 + 4);
    f4 qb0 = *(const f4*)(ap + 16 + h * 8);
    f4 qb1 = *(const f4*)(ap + 16 + h * 8 + 4);
    float ss = 0.f;
#pragma unroll
    for (int e = 0; e < 4; e++)
      ss += qa0[e] * qa0[e] + qa1[e] * qa1[e] + qb0[e] * qb0[e] + qb1[e] * qb1[e];
    ss += __shfl_xor(ss, 32);
    const float qsc = escale / fmaxf(sqrtf(ss), 1e-12f);
    pack_hilo8(qa0[0] * qsc, qa0[1] * qsc, qa0[2] * qsc, qa0[3] * qsc,
               qa1[0] * qsc, qa1[1] * qsc, qa1[2] * qsc, qa1[3] * qsc,
               qfh[g][0], qfl[g][0]);
    pack_hilo8(qb0[0] * qsc, qb0[1] * qsc, qb0[2] * qsc, qb0[3] * qsc,
               qb1[0] * qsc, qb1[1] * qsc, qb1[2] * qsc, qb1[3] * qsc,
               qfh[g][1], qfl[g][1]);
  }

  f32x16 o0 = {}, o1 = {};
  float rs0 = 0.f, rs1 = 0.f;
#pragma unroll 1
  for (int kt = 0; kt < 8; kt++) {
    const int key = wv * 256 + kt * 32 + l31;
    const float* kp = qkvs + (rowbase + (key >> 4) * 64 + (key & 15)) * 384 + 128 + head * 32;
    f4 ka0 = *(const f4*)(kp + h * 8);
    f4 ka1 = *(const f4*)(kp + h * 8 + 4);
    f4 kb0 = *(const f4*)(kp + 16 + h * 8);
    f4 kb1 = *(const f4*)(kp + 16 + h * 8 + 4);
    float ss = 0.f;
#pragma unroll
    for (int e = 0; e < 4; e++)
      ss += ka0[e] * ka0[e] + ka1[e] * ka1[e] + kb0[e] * kb0[e] + kb1[e] * kb1[e];
    ss += __shfl_xor(ss, 32);
    const float kinv = 1.f / fmaxf(sqrtf(ss), 1e-12f);
    bf16x8 kh0, kl0, kh1, kl1;
    pack_hilo8(ka0[0] * kinv, ka0[1] * kinv, ka0[2] * kinv, ka0[3] * kinv,
               ka1[0] * kinv, ka1[1] * kinv, ka1[2] * kinv, ka1[3] * kinv, kh0, kl0);
    pack_hilo8(kb0[0] * kinv, kb0[1] * kinv, kb0[2] * kinv, kb0[3] * kinv,
               kb1[0] * kinv, kb1[1] * kinv, kb1[2] * kinv, kb1[3] * kinv, kh1, kl1);

    f32x16 st0 = {}, st1 = {};
    st0 = __builtin_amdgcn_mfma_f32_32x32x16_bf16(kh0, qfh[0][0], st0, 0, 0, 0);
    st0 = __builtin_amdgcn_mfma_f32_32x32x16_bf16(kh1, qfh[0][1], st0, 0, 0, 0);
    st0 = __builtin_amdgcn_mfma_f32_32x32x16_bf16(kh0, qfl[0][0], st0, 0, 0, 0);
    st0 = __builtin_amdgcn_mfma_f32_32x32x16_bf16(kh1, qfl[0][1], st0, 0, 0, 0);
    st0 = __builtin_amdgcn_mfma_f32_32x32x16_bf16(kl0, qfh[0][0], st0, 0, 0, 0);
    st0 = __builtin_amdgcn_mfma_f32_32x32x16_bf16(kl1, qfh[0][1], st0, 0, 0, 0);
    st1 = __builtin_amdgcn_mfma_f32_32x32x16_bf16(kh0, qfh[1][0], st1, 0, 0, 0);
    st1 = __builtin_amdgcn_mfma_f32_32x32x16_bf16(kh1, qfh[1][1], st1, 0, 0, 0);
    st1 = __builtin_amdgcn_mfma_f32_32x32x16_bf16(kh0, qfl[1][0], st1, 0, 0, 0);
    st1 = __builtin_amdgcn_mfma_f32_32x32x16_bf16(kh1, qfl[1][1], st1, 0, 0, 0);
    st1 = __builtin_amdgcn_mfma_f32_32x32x16_bf16(kl0, qfh[1][0], st1, 0, 0, 0);
    st1 = __builtin_amdgcn_mfma_f32_32x32x16_bf16(kl1, qfh[1][1], st1, 0, 0, 0);

    float p0[16], p1[16];
    {
      const float* bp = bias1x + ((size_t)(head * 64 + l31)) * 1024 + wv * 256 + kt * 32 + h * 4;
      f4 b0 = *(const f4*)(bp);
      f4 b1 = *(const f4*)(bp + 8);
      f4 b2 = *(const f4*)(bp + 16);
      f4 b3 = *(const f4*)(bp + 24);
      float a = 0.f;
#pragma unroll
      for (int r = 0; r < 16; r++) {
        const float bb = (r < 4) ? b0[r & 3] : (r < 8) ? b1[r & 3] : (r < 12) ? b2[r & 3] : b3[r & 3];
        const float pv = __expf(st0[r] + bb - M);
        p0[r] = pv;
        a += pv;
      }
      rs0 += a;
    }
    {
      const float* bp = bias1x + ((size_t)(head * 64 + 32 + l31)) * 1024 + wv * 256 + kt * 32 + h * 4;
      f4 b0 = *(const f4*)(bp);
      f4 b1 = *(const f4*)(bp + 8);
      f4 b2 = *(const f4*)(bp + 16);
      f4 b3 = *(const f4*)(bp + 24);
      float a = 0.f;
#pragma unroll
      for (int r = 0; r < 16; r++) {
        const float bb = (r < 4) ? b0[r & 3] : (r < 8) ? b1[r & 3] : (r < 12) ? b2[r & 3] : b3[r & 3];
        const float pv = __expf(st1[r] + bb - M);
        p1[r] = pv;
        a += pv;
      }
      rs1 += a;
    }

#pragma unroll
    for (int s = 0; s < 2; s++) {
      const int vrow0 = (wv * 256 + kt * 32 + s * 16) >> 4;
      const float* rowp = qkvs + (rowbase + (size_t)vrow0 * 64) * 384 + 256 + head * 32 + l31;
      float v8[8];
#pragma unroll
      for (int e = 0; e < 8; e++) v8[e] = rowp[(size_t)(h * 8 + e) * 384];
      bf16x8 vh, vl;
      pack_hilo8(v8[0], v8[1], v8[2], v8[3], v8[4], v8[5], v8[6], v8[7], vh, vl);
      bf16x8 pah, pal;
      if (s == 0)
        pack_pa(p0[0], p0[1], p0[2], p0[3], p0[4], p0[5], p0[6], p0[7], pah, pal);
      else
        pack_pa(p0[8], p0[9], p0[10], p0[11], p0[12], p0[13], p0[14], p0[15], pah, pal);
      o0 = __builtin_amdgcn_mfma_f32_32x32x16_bf16(pah, vh, o0, 0, 0, 0);
      o0 = __builtin_amdgcn_mfma_f32_32x32x16_bf16(pah, vl, o0, 0, 0, 0);
      o0 = __builtin_amdgcn_mfma_f32_32x32x16_bf16(pal, vh, o0, 0, 0, 0);
      if (s == 0)
        pack_pa(p1[0], p1[1], p1[2], p1[3], p1[4], p1[5], p1[6], p1[7], pah, pal);
      else
        pack_pa(p1[8], p1[9], p1[10], p1[11], p1[12], p1[13], p1[14], p1[15], pah, pal);
      o1 = __builtin_amdgcn_mfma_f32_32x32x16_bf16(pah, vh, o1, 0, 0, 0);
      o1 = __builtin_amdgcn_mfma_f32_32x32x16_bf16(pah, vl, o1, 0, 0, 0);
      o1 = __builtin_amdgcn_mfma_f32_32x32x16_bf16(pal, vh, o1, 0, 0, 0);
    }
  }

  rs0 += __shfl_xor(rs0, 32);
  rs1 += __shfl_xor(rs1, 32);
  if (h == 0) {
    rsp[wv][l31] = rs0;
    rsp[wv][32 + l31] = rs1;
  }
#pragma unroll
  for (int r = 0; r < 16; r++) {
    const int qr = (r & 3) + 8 * (r >> 2) + 4 * h;
    opart[wv][qr][l31] = o0[r];
    opart[wv][32 + qr][l31] = o1[r];
  }
  __syncthreads();
  {
    const int q = tid >> 2, d0 = (tid & 3) * 8;
    const float inv = 1.f / (rsp[0][q] + rsp[1][q] + rsp[2][q] + rsp[3][q]);
    float* tp = tbuf + (size_t)blockIdx.x * 2048 + q * 32 + d0;
#pragma unroll
    for (int i = 0; i < 8; i++) {
      const int d = d0 + i;
      tp[i] = (opart[0][q][d] + opart[1][q][d] + opart[2][q][d] + opart[3][q][d]) * inv;
    }
  }
}

// ---------------------------------------------------------------- stripe stage 2 (MFMA)
// block = (b, wj, head): 1024 q x 64 anchors, values = t. Wave owns 256 q (8 groups of 32).
// Anchor A-frags + T B-frags built once per wave and held in registers.
__global__ __launch_bounds__(256) void k_stripe2_mfma(
    const float* __restrict__ qkvs, const float* __restrict__ anch,
    const float* __restrict__ tbuf, const float* __restrict__ bias2x,
    const float* __restrict__ ls, float* __restrict__ outp) {
  __shared__ float t_s[2048];
  const int head = blockIdx.x & 3, sb = blockIdx.x >> 2;
  const int b = sb >> 2, wj = sb & 3;
  const size_t rowbase = (size_t)b * 4096 + wj * 16;
  const size_t abase = (size_t)b * 256 + wj * 4;
  const int tid = threadIdx.x;
  const int l = tid & 63, wv = tid >> 6;
  const int h = l >> 5, l31 = l & 31;
  const float escale = __expf(fminf(ls[head], LOGIT_MAX_F));
  const float M = escale + 16.f;
  {  // stage T (f32, 8 KB)
    const float* tp = tbuf + (size_t)blockIdx.x * 2048 + tid * 8;
    *(f4*)(&t_s[tid * 8]) = *(const f4*)(tp);
    *(f4*)(&t_s[tid * 8 + 4]) = *(const f4*)(tp + 4);
  }
  // anchor A-frags (K side): 2 chunks of 32 anchors, normalized
  bf16x8 akh[2][2], akl[2][2];
#pragma unroll
  for (int c = 0; c < 2; c++) {
    const int a = c * 32 + l31;
    const float* ap = anch + (abase + (a >> 2) * 16 + (a & 3)) * 128 + head * 32;
    f4 a0 = *(const f4*)(ap + h * 8);
    f4 a1 = *(const f4*)(ap + h * 8 + 4);
    f4 b0 = *(const f4*)(ap + 16 + h * 8);
    f4 b1 = *(const f4*)(ap + 16 + h * 8 + 4);
    float ss = 0.f;
#pragma unroll
    for (int e = 0; e < 4; e++)
      ss += a0[e] * a0[e] + a1[e] * a1[e] + b0[e] * b0[e] + b1[e] * b1[e];
    ss += __shfl_xor(ss, 32);
    const float ai = 1.f / fmaxf(sqrtf(ss), 1e-12f);
    pack_hilo8(a0[0] * ai, a0[1] * ai, a0[2] * ai, a0[3] * ai,
               a1[0] * ai, a1[1] * ai, a1[2] * ai, a1[3] * ai, akh[c][0], akl[c][0]);
    pack_hilo8(b0[0] * ai, b0[1] * ai, b0[2] * ai, b0[3] * ai,
               b1[0] * ai, b1[1] * ai, b1[2] * ai, b1[3] * ai, akh[c][1], akl[c][1]);
  }
  __syncthreads();
  // T B-frags: 4 k-steps of 16 anchors; lane needs T[a = s*16 + h*8 + e][d = l31]
  bf16x8 tfh[4], tfl[4];
#pragma unroll
  for (int s = 0; s < 4; s++) {
    float v8[8];
#pragma unroll
    for (int e = 0; e < 8; e++) v8[e] = t_s[(s * 16 + h * 8 + e) * 32 + l31];
    pack_hilo8(v8[0], v8[1], v8[2], v8[3], v8[4], v8[5], v8[6], v8[7], tfh[s], tfl[s]);
  }

#pragma unroll 1
  for (int qg = 0; qg < 8; qg++) {
    const int q = wv * 256 + qg * 32 + l31;
    const float* qp = qkvs + (rowbase + (q >> 4) * 64 + (q & 15)) * 384 + head * 32;
    f4 qa0 = *(const f4*)(qp + h * 8);
    f4 qa1 = *(const f4*)(qp + h * 8 + 4);
    f4 qb0 = *(const f4*)(qp + 16 + h * 8);
    f4 qb1 = *(const f4*)(qp + 16 + h * 8 + 4);
    float ss = 0.f;
#pragma unroll
    for (int e = 0; e < 4; e++)
      ss += qa0[e] * qa0[e] + qa1[e] * qa1[e] + qb0[e] * qb0[e] + qb1[e] * qb1[e];
    ss += __shfl_xor(ss, 32);
    const float qsc = escale / fmaxf(sqrtf(ss), 1e-12f);
    bf16x8 qbh[2], qbl[2];
    pack_hilo8(qa0[0] * qsc, qa0[1] * qsc, qa0[2] * qsc, qa0[3] * qsc,
               qa1[0] * qsc, qa1[1] * qsc, qa1[2] * qsc, qa1[3] * qsc, qbh[0], qbl[0]);
    pack_hilo8(qb0[0] * qsc, qb0[1] * qsc, qb0[2] * qsc, qb0[3] * qsc,
               qb1[0] * qsc, qb1[1] * qsc, qb1[2] * qsc, qb1[3] * qsc, qbh[1], qbl[1]);

    f32x16 st0 = {}, st1 = {};
    st0 = __builtin_amdgcn_mfma_f32_32x32x16_bf16(akh[0][0], qbh[0], st0, 0, 0, 0);
    st0 = __builtin_amdgcn_mfma_f32_32x32x16_bf16(akh[0][1], qbh[1], st0, 0, 0, 0);
    st0 = __builtin_amdgcn_mfma_f32_32x32x16_bf16(akh[0][0], qbl[0], st0, 0, 0, 0);
    st0 = __builtin_amdgcn_mfma_f32_32x32x16_bf16(akh[0][1], qbl[1], st0, 0, 0, 0);
    st0 = __builtin_amdgcn_mfma_f32_32x32x16_bf16(akl[0][0], qbh[0], st0, 0, 0, 0);
    st0 = __builtin_amdgcn_mfma_f32_32x32x16_bf16(akl[0][1], qbh[1], st0, 0, 0, 0);
    st1 = __builtin_amdgcn_mfma_f32_32x32x16_bf16(akh[1][0], qbh[0], st1, 0, 0, 0);
    st1 = __builtin_amdgcn_mfma_f32_32x32x16_bf16(akh[1][1], qbh[1], st1, 0, 0, 0);
    st1 = __builtin_amdgcn_mfma_f32_32x32x16_bf16(akh[1][0], qbl[0], st1, 0, 0, 0);
    st1 = __builtin_amdgcn_mfma_f32_32x32x16_bf16(akh[1][1], qbl[1], st1, 0, 0, 0);
    st1 = __builtin_amdgcn_mfma_f32_32x32x16_bf16(akl[1][0], qbh[0], st1, 0, 0, 0);
    st1 = __builtin_amdgcn_mfma_f32_32x32x16_bf16(akl[1][1], qbh[1], st1, 0, 0, 0);

    float p0[16], p1[16];
    float rs = 0.f;
    {
      const float* bp = bias2x + ((size_t)(head * 1024 + q)) * 64 + h * 4;
      f4 b0 = *(const f4*)(bp);
      f4 b1 = *(const f4*)(bp + 8);
      f4 b2 = *(const f4*)(bp + 16);
      f4 b3 = *(const f4*)(bp + 24);
#pragma unroll
      for (int r = 0; r < 16; r++) {
        const float bb = (r < 4) ? b0[r & 3] : (r < 8) ? b1[r & 3] : (r < 12) ? b2[r & 3] : b3[r & 3];
        const float pv = __expf(st0[r] + bb - M);
        p0[r] = pv;
        rs += pv;
      }
      f4 c0 = *(const f4*)(bp + 32);
      f4 c1 = *(const f4*)(bp + 40);
      f4 c2 = *(const f4*)(bp + 48);
      f4 c3 = *(const f4*)(bp + 56);
#pragma unroll
      for (int r = 0; r < 16; r++) {
        const float bb = (r < 4) ? c0[r & 3] : (r < 8) ? c1[r & 3] : (r < 12) ? c2[r & 3] : c3[r & 3];
        const float pv = __expf(st1[r] + bb - M);
        p1[r] = pv;
        rs += pv;
      }
    }
    rs += __shfl_xor(rs, 32);
    const float inv = 1.f / rs;

    f32x16 o = {};
#pragma unroll
    for (int s = 0; s < 4; s++) {
      bf16x8 pah, pal;
      if (s == 0)      pack_pa(p0[0], p0[1], p0[2], p0[3], p0[4], p0[5], p0[6], p0[7], pah, pal);
      else if (s == 1) pack_pa(p0[8], p0[9], p0[10], p0[11], p0[12], p0[13], p0[14], p0[15], pah, pal);
      else if (s == 2) pack_pa(p1[0], p1[1], p1[2], p1[3], p1[4], p1[5], p1[6], p1[7], pah, pal);
      else             pack_pa(p1[8], p1[9], p1[10], p1[11], p1[12], p1[13], p1[14], p1[15], pah, pal);
      o = __builtin_amdgcn_mfma_f32_32x32x16_bf16(pah, tfh[s], o, 0, 0, 0);
      o = __builtin_amdgcn_mfma_f32_32x32x16_bf16(pah, tfl[s], o, 0, 0, 0);
      o = __builtin_amdgcn_mfma_f32_32x32x16_bf16(pal, tfh[s], o, 0, 0, 0);
    }
#pragma unroll
    for (int r = 0; r < 16; r++) {
      const int qr = (r & 3) + 8 * (r >> 2) + 4 * h;
      const float iv = __shfl(inv, qr);
      const int qo = wv * 256 + qg * 32 + qr;
      outp[(rowbase + (qo >> 4) * 64 + (qo & 15)) * 256 + 128 + head * 32 + l31] = o[r] * iv;
    }
  }
}

// ---------------------------------------------------------------- launch
extern "C" void kernel_launch(void* const* d_in, const int* in_sizes, int n_in,
                              void* d_out, int out_size, void* d_ws, size_t ws_size,
                              hipStream_t stream) {
  (void)in_sizes; (void)n_in; (void)out_size;
  const float* x        = (const float*)d_in[0];
  const float* w_qkv    = (const float*)d_in[1];
  const float* b_qkv    = (const float*)d_in[2];
  const float* w_anchor = (const float*)d_in[3];
  const float* b_anchor = (const float*)d_in[4];
  const float* ls_w     = (const float*)d_in[5];
  const float* cw1_w    = (const float*)d_in[6];
  const float* cb1_w    = (const float*)d_in[7];
  const float* cw2_w    = (const float*)d_in[8];
  const float* ls_s1    = (const float*)d_in[9];
  const float* cw1_s1   = (const float*)d_in[10];
  const float* cb1_s1   = (const float*)d_in[11];
  const float* cw2_s1   = (const float*)d_in[12];
  const float* ls_s2    = (const float*)d_in[13];
  const float* cw1_s2   = (const float*)d_in[14];
  const float* cb1_s2   = (const float*)d_in[15];
  const float* cw2_s2   = (const float*)d_in[16];
  const float* w_proj   = (const float*)d_in[17];
  const float* b_proj   = (const float*)d_in[18];
  float* out = (float*)d_out;

  // ---- adaptive chunking over batch
  const size_t fixed_bytes =
      (size_t)4096 * 256 * 4 +              // pooled
      (size_t)4096 * 128 * 4 +              // anch
      (size_t)961 * 16 + (size_t)1501 * 16 * 2 +
      (size_t)(768 + 256) * 256 * 2 * 2 +   // transposed bf16 weights hi+lo
      (size_t)4 * 256 * 256 * 4 +           // expanded window bias
      (size_t)4 * 64 * 1024 * 4 +           // expanded stripe1 bias
      (size_t)4 * 1024 * 64 * 4 +           // expanded stripe2 bias
      64 * 256;                             // slack
  const size_t per_nb = (size_t)4096 * 384 * 4 + (size_t)16 * 2048 * 4 +
                        (size_t)4096 * 256 * 2 * 2;
  int NB = 16;
  while (NB > 1) {
    size_t need = fixed_bytes + (size_t)NB * per_nb;
    if (need <= ws_size) break;
    NB >>= 1;
  }
  const int nchunks = 16 / NB;

  char* ws = (char*)d_ws;
  size_t off = 0;
  auto take = [&](size_t bytes) {
    char* p = ws + off;
    off += (bytes + 255) & ~(size_t)255;
    return p;
  };
  float* pooled = (float*)take((size_t)4096 * 256 * 4);
  float* anch   = (float*)take((size_t)4096 * 128 * 4);
  float* sbt_w  = (float*)take((size_t)961 * 16);
  float* sbt_s1 = (float*)take((size_t)1501 * 16);
  float* sbt_s2 = (float*)take((size_t)1501 * 16);
  float* bias2w = (float*)take((size_t)4 * 256 * 256 * 4);
  float* bias1x = (float*)take((size_t)4 * 64 * 1024 * 4);
  float* bias2x = (float*)take((size_t)4 * 1024 * 64 * 4);
  unsigned short* wqh = (unsigned short*)take((size_t)768 * 256 * 2);
  unsigned short* wql = (unsigned short*)take((size_t)768 * 256 * 2);
  unsigned short* wph = (unsigned short*)take((size_t)256 * 256 * 2);
  unsigned short* wpl = (unsigned short*)take((size_t)256 * 256 * 2);
  float* tbuf   = (float*)take((size_t)NB * 16 * 2048 * 4);
  unsigned short* xhi = (unsigned short*)take((size_t)NB * 4096 * 256 * 2);
  unsigned short* xlo = (unsigned short*)take((size_t)NB * 4096 * 256 * 2);
  float* qkvh   = (float*)take((size_t)NB * 4096 * 384 * 4);

  // ---- one-time prep
  k_cpb<<<961, 64, 0, stream>>>(cw1_w, cb1_w, cw2_w, sbt_w, 31, 1.f / 15.f, 1.f / 15.f, -15, -15);
  k_cpb<<<1501, 64, 0, stream>>>(cw1_s1, cb1_s1, cw2_s1, sbt_s1, 19, 1.f / 39.f, 1.f / 9.f, -39, -9);
  k_cpb<<<1501, 64, 0, stream>>>(cw1_s2, cb1_s2, cw2_s2, sbt_s2, 19, 1.f / 39.f, 1.f / 9.f, -39, -9);
  k_bias_expand<<<1024, 256, 0, stream>>>(sbt_w, bias2w);
  k_bias1x<<<256, 256, 0, stream>>>(sbt_s1, bias1x);
  k_bias2x<<<4096, 64, 0, stream>>>(sbt_s2, bias2x);
  k_cvt_wt<<<768, 256, 0, stream>>>(w_qkv, wqh, wql, 768);
  k_cvt_wt<<<256, 256, 0, stream>>>(w_proj, wph, wpl, 256);
  k_pool<<<4096, 256, 0, stream>>>(x, pooled);
  k_gemm<<<(4096 / 64) * 2, 256, 0, stream>>>(pooled, w_anchor, b_anchor, anch, 4096, 128, 256, 128);

  // ---- chunked over batch
  const int M = NB * 4096;
  for (int c = 0; c < nchunks; c++) {
    const float* xc = x + (size_t)c * NB * 4096 * 256;
    float* outc = out + (size_t)c * NB * 4096 * 256;
    const float* anchc = anch + (size_t)c * NB * 256 * 128;
    k_cvt<<<NB * 512, 256, 0, stream>>>(xc, xhi, xlo);
    // window half (qkv channels 0..383)
    k_gemm_bf16pair<<<(M / 128) * 3, 256, 0, stream>>>(xhi, xlo, wqh, wql, b_qkv, qkvh, M, 384);
    k_win_attn_mfma<<<NB * 64, 256, 0, stream>>>(qkvh, bias2w, ls_w, outc);
    // stripe half (qkv channels 384..767) overwrites qkvh
    k_gemm_bf16pair<<<(M / 128) * 3, 256, 0, stream>>>(xhi, xlo, wqh + 384 * 256, wql + 384 * 256,
                                                       b_qkv + 384, qkvh, M, 384);
    k_stripe1_mfma<<<NB * 16, 256, 0, stream>>>(qkvh, anchc, bias1x, ls_s1, tbuf);
    k_stripe2_mfma<<<NB * 16, 256, 0, stream>>>(qkvh, anchc, tbuf, bias2x, ls_s2, outc);
  }
  // ---- final projection (reads bf16 copy of out, writes out -> no aliasing hazard)
  for (int c = 0; c < nchunks; c++) {
    float* outc = out + (size_t)c * NB * 4096 * 256;
    k_cvt<<<NB * 512, 256, 0, stream>>>(outc, xhi, xlo);
    k_gemm_bf16pair<<<(M / 128) * 2, 256, 0, stream>>>(xhi, xlo, wph, wpl, b_proj, outc, M, 256);
  }
}